// Round 18
// baseline (767.422 us; speedup 1.0000x reference)
//
#include <hip/hip_runtime.h>
#include <hip/hip_fp16.h>
#include <cstdint>

// MessagePassing — 2-slab interleaved MFMA edge-MLP (channel-major w) +
// streaming aggregation, MFMA node_pre, fp16 f-gathers, 8-node post.
// N=20000, E=320000. CS=64, CV=32, CM=96, WN=192, FCH=64.

#define CS 64
#define CV 32
#define CM 96
#define WN 192
#define FCH 64
#define WPAD 72     // padded K-stride (halfs) for LDS weight tiles
#define CHUNK 64    // src/ea staged per LDS batch in agg
#define NSLABS 2    // slabs per conv

using f16x8 = __attribute__((ext_vector_type(8))) _Float16;
using f32x4 = __attribute__((ext_vector_type(4))) float;

__device__ __forceinline__ float siluf(float x){ return x / (1.f + __expf(-x)); }

constexpr float INV8       = 0.125f;
constexpr float INV_SQRT32 = 0.17677669529663687f;
constexpr float INV_SQRT96 = 0.10206207261596575f;
constexpr float INV_SQRT3  = 0.5773502691896258f;

// ---------------- histogram of edge_dst ----------------
__global__ void hist_kernel(const int* __restrict__ edst, int* __restrict__ cnt, int E){
    int e = blockIdx.x*blockDim.x + threadIdx.x;
    if (e < E) atomicAdd(&cnt[edst[e]], 1);
}

// ---------------- single-block exclusive scan ----------------
__global__ void scan_kernel(const int* __restrict__ cnt, int* __restrict__ row_start,
                            int* __restrict__ cursor, int n, int E){
    __shared__ int part[1024];
    const int t = threadIdx.x;
    const int C = (n + 1023) / 1024;
    int local[32];
    int base = t*C;
    int s = 0;
    for (int j = 0; j < C && j < 32; ++j){
        int idx = base + j;
        int v = (idx < n) ? cnt[idx] : 0;
        local[j] = s; s += v;
    }
    part[t] = s;
    __syncthreads();
    for (int off = 1; off < 1024; off <<= 1){
        int v = (t >= off) ? part[t-off] : 0;
        __syncthreads();
        part[t] += v;
        __syncthreads();
    }
    int pre = (t == 0) ? 0 : part[t-1];
    for (int j = 0; j < C && j < 32; ++j){
        int idx = base + j;
        if (idx < n){ int rs = pre + local[j]; row_start[idx] = rs; cursor[idx] = rs; }
    }
    if (t == 0) row_start[n] = E;
}

// ---------------- scatter: perm + sorted eattr/esrc sidecars ----------------
__global__ void scatter_kernel(const int* __restrict__ edst, const int* __restrict__ esrc,
                               const float4* __restrict__ eattr,
                               int* __restrict__ cursor, int* __restrict__ perm,
                               float4* __restrict__ eattr_s, int* __restrict__ esrc_s, int E){
    int e = blockIdx.x*blockDim.x + threadIdx.x;
    if (e < E){
        int p = atomicAdd(&cursor[edst[e]], 1);
        perm[p] = e; eattr_s[p] = eattr[e]; esrc_s[p] = esrc[e];
    }
}

__global__ void isd_kernel(const int* __restrict__ cnt, float* __restrict__ isd, int n){
    int i = blockIdx.x*blockDim.x + threadIdx.x;
    if (i < n) isd[i] = rsqrtf((float)cnt[i]);
}

// ---------------- weight prep (edge MLP) ----------------
__global__ void wprep(const float* __restrict__ Wfa1, const float* __restrict__ Wfb1,
                      const float* __restrict__ Wfa2, const float* __restrict__ Wfb2,
                      __half* __restrict__ Wc1, __half* __restrict__ Wc2){
    int t = blockIdx.x*blockDim.x + threadIdx.x;
    if (t < 64*WPAD){
        int c = t / WPAD, k = t - c*WPAD;
        float v1 = (k < 64) ? Wfa1[k*64 + c]*INV8 : 0.f;
        float v2 = (k < 64) ? Wfa2[k*64 + c]*INV8 : 0.f;
        Wc1[t] = __float2half(v1); Wc2[t] = __float2half(v2);
    } else if (t < 64*WPAD + 192*WPAD){
        int q = t - 64*WPAD; int o = q / WPAD, k = q - o*WPAD;
        float v1 = (k < 64) ? Wfb1[k*192 + o]*INV8 : 0.f;
        float v2 = (k < 64) ? Wfb2[k*192 + o]*INV8 : 0.f;
        Wc1[t] = __float2half(v1); Wc2[t] = __float2half(v2);
    }
}

// ---------------- weight prep (node_pre) ----------------
__global__ void wprep_pre(
    const float* __restrict__ l1s1, const float* __restrict__ scs1,
    const float* __restrict__ l1v1, const float* __restrict__ scv1,
    const float* __restrict__ l1s2, const float* __restrict__ scs2,
    const float* __restrict__ l1v2, const float* __restrict__ scv2,
    __half* __restrict__ Bs1, __half* __restrict__ Bs2,
    __half* __restrict__ Bv1, __half* __restrict__ Bv2)
{
    int t = blockIdx.x*blockDim.x + threadIdx.x;
    if (t < 160*72){
        int col = t/72, k = t - col*72;
        float v = 0.f;
        if (k < 64) v = (col < 64 ? l1s1[k*64 + col] : scs1[k*96 + (col-64)]) * INV8;
        Bs1[t] = __float2half(v);
    } else if (t < 160*72 + 128*72){
        int q = t - 160*72; int col = q/72, k = q - col*72;
        float v = 0.f;
        if (k < 64) v = (col < 64 ? l1s2[k*64 + col] : scs2[k*64 + (col-64)]) * INV8;
        Bs2[q] = __float2half(v);
    } else if (t < 160*72 + 128*72 + 64*40){
        int q = t - (160*72 + 128*72); int col = q/40, k = q - col*40;
        float v = 0.f;
        if (k < 32) v = (col < 32 ? l1v1[k*32 + col] : scv1[k*32 + (col-32)]) * INV_SQRT32;
        Bv1[q] = __float2half(v);
    } else if (t < 160*72 + 128*72 + 2*64*40){
        int q = t - (160*72 + 128*72 + 64*40); int col = q/40, k = q - col*40;
        float v = 0.f;
        if (k < 32) v = (col < 32 ? l1v2[k*32 + col] : scv2[k*32 + (col-32)]) * INV_SQRT32;
        Bv2[q] = __float2half(v);
    }
}

// ---------------- MFMA node pre-transform: 64 nodes/block ----------------
template<int OS>
__global__ __launch_bounds__(256) void node_pre_mfma(
    const float* __restrict__ s, int ss,
    const float* __restrict__ v, int vs,
    const float* __restrict__ attr,
    const __half* __restrict__ Bs, const __half* __restrict__ Bv,
    __half* __restrict__ f_s, float* __restrict__ sc_s,
    __half* __restrict__ f_v, float* __restrict__ sc_v, int N)
{
    constexpr int SC = 64 + OS;
    __shared__ __align__(16) __half sAh[64*168];
    __shared__ __align__(16) __half lBs[SC*72];
    __shared__ __align__(16) __half lBv[64*40];
    __shared__ float s_at[64];

    const int tid = threadIdx.x;
    const int n0 = blockIdx.x*64;
    const int nmax = min(64, N - n0);

    for (int i = tid; i < (SC*72)/8; i += 256)
        reinterpret_cast<uint4*>(lBs)[i] = reinterpret_cast<const uint4*>(Bs)[i];
    for (int i = tid; i < (64*40)/8; i += 256)
        reinterpret_cast<uint4*>(lBv)[i] = reinterpret_cast<const uint4*>(Bv)[i];
    for (int i = tid; i < 64*64; i += 256){
        int n = i >> 6, k = i & 63;
        float x = (n < nmax) ? s[(size_t)(n0+n)*ss + k] : 0.f;
        sAh[n*168 + k] = __float2half(x);
    }
    for (int i = tid; i < 64*96; i += 256){
        int n = i/96, k = i - n*96;
        float x = (n < nmax) ? v[(size_t)(n0+n)*vs + k] : 0.f;
        sAh[n*168 + 64 + k] = __float2half(x);
    }
    if (tid < 64) s_at[tid] = (tid < nmax) ? attr[n0 + tid] : 0.f;
    __syncthreads();

    const int wv = tid >> 6, l = tid & 63;
    const int lm = l & 15, kg = l >> 4;
    const int rbase = wv*16;
    const int orow = rbase + kg*4;

    f16x8 xf0 = *reinterpret_cast<const f16x8*>(&sAh[(rbase+lm)*168 + kg*8]);
    f16x8 xf1 = *reinterpret_cast<const f16x8*>(&sAh[(rbase+lm)*168 + 32 + kg*8]);
    #pragma unroll
    for (int nt = 0; nt < SC/16; ++nt){
        f16x8 wb0 = *reinterpret_cast<const f16x8*>(&lBs[(nt*16+lm)*72 + kg*8]);
        f16x8 wb1 = *reinterpret_cast<const f16x8*>(&lBs[(nt*16+lm)*72 + 32 + kg*8]);
        f32x4 acc = {0.f,0.f,0.f,0.f};
        acc = __builtin_amdgcn_mfma_f32_16x16x32_f16(xf0, wb0, acc, 0, 0, 0);
        acc = __builtin_amdgcn_mfma_f32_16x16x32_f16(xf1, wb1, acc, 0, 0, 0);
        const int col = nt*16 + lm;
        #pragma unroll
        for (int r = 0; r < 4; ++r){
            int nl = orow + r;
            if (nl < nmax){
                float val = acc[r]*s_at[nl];
                if (col < 64) f_s[(size_t)(n0+nl)*64 + col] = __float2half(val);
                else          sc_s[(size_t)(n0+nl)*OS + (col-64)] = val;
            }
        }
    }

    #pragma unroll
    for (int c = 0; c < 3; ++c){
        f16x8 xa;
        #pragma unroll
        for (int j = 0; j < 8; ++j)
            xa[j] = (_Float16)sAh[(rbase+lm)*168 + 64 + (kg*8+j)*3 + c];
        #pragma unroll
        for (int nt = 0; nt < 4; ++nt){
            f16x8 wb = *reinterpret_cast<const f16x8*>(&lBv[(nt*16+lm)*40 + kg*8]);
            f32x4 acc = {0.f,0.f,0.f,0.f};
            acc = __builtin_amdgcn_mfma_f32_16x16x32_f16(xa, wb, acc, 0, 0, 0);
            const int col = nt*16 + lm;
            #pragma unroll
            for (int r = 0; r < 4; ++r){
                int nl = orow + r;
                if (nl < nmax){
                    float val = acc[r]*s_at[nl];
                    if (col < 32) f_v[(size_t)(n0+nl)*96 + col*3 + c] = __float2half(val);
                    else          sc_v[(size_t)(n0+nl)*96 + (col-32)*3 + c] = val;
                }
            }
        }
    }
}

// ---------------- MFMA edge MLP over one slab: CHANNEL-MAJOR w ----------------
// w_T[widx][slot_rel]: wstride halfs per channel row. acc[0..3] are 4
// consecutive slots at fixed channel -> one 8B packed store (orow%4==0).
__global__ __launch_bounds__(256) void mlp_gemm_slab(
    const int* __restrict__ row_start, int n0, int n1,
    const int* __restrict__ perm, const float* __restrict__ escal,
    const __half* __restrict__ Wc, __half* __restrict__ w_T, size_t wstride, int E)
{
    __shared__ __half lWa[64*WPAD];
    __shared__ __half lWb[192*WPAD];
    __shared__ __half hsm[4][16*WPAD];

    const int rs_slab = row_start[n0];
    const int re_slab = row_start[n1];
    if (rs_slab + (int)blockIdx.x*64 >= re_slab) return;

    const int tid = threadIdx.x;
    {
        const uint4* src4 = reinterpret_cast<const uint4*>(Wc);
        uint4* dA = reinterpret_cast<uint4*>(lWa);
        uint4* dB = reinterpret_cast<uint4*>(lWb);
        for (int i = tid; i < (64*WPAD)/8; i += 256) dA[i] = src4[i];
        for (int i = tid; i < (192*WPAD)/8; i += 256) dB[i] = src4[(64*WPAD)/8 + i];
    }
    __syncthreads();

    const int wv = tid >> 6, l = tid & 63;
    const int lm = l & 15, kg = l >> 4;

    for (int tile = rs_slab + blockIdx.x*64; tile < re_slab; tile += gridDim.x*64){
        const int base = tile + wv*16;
        int slot = base + lm; if (slot >= re_slab) slot = re_slab - 1;
        const int e = perm[slot];
        const float* xp = escal + (size_t)e*64 + kg*8;
        f16x8 xf0, xf1;
        {
            float4 a0 = *reinterpret_cast<const float4*>(xp);
            float4 a1 = *reinterpret_cast<const float4*>(xp + 4);
            float4 b0 = *reinterpret_cast<const float4*>(xp + 32);
            float4 b1 = *reinterpret_cast<const float4*>(xp + 36);
            xf0[0]=(_Float16)a0.x; xf0[1]=(_Float16)a0.y; xf0[2]=(_Float16)a0.z; xf0[3]=(_Float16)a0.w;
            xf0[4]=(_Float16)a1.x; xf0[5]=(_Float16)a1.y; xf0[6]=(_Float16)a1.z; xf0[7]=(_Float16)a1.w;
            xf1[0]=(_Float16)b0.x; xf1[1]=(_Float16)b0.y; xf1[2]=(_Float16)b0.z; xf1[3]=(_Float16)b0.w;
            xf1[4]=(_Float16)b1.x; xf1[5]=(_Float16)b1.y; xf1[6]=(_Float16)b1.z; xf1[7]=(_Float16)b1.w;
        }

        #pragma unroll
        for (int nt = 0; nt < 4; ++nt){
            f16x8 wa0 = *reinterpret_cast<const f16x8*>(&lWa[(nt*16 + lm)*WPAD + kg*8]);
            f16x8 wa1 = *reinterpret_cast<const f16x8*>(&lWa[(nt*16 + lm)*WPAD + 32 + kg*8]);
            f32x4 acc = {0.f,0.f,0.f,0.f};
            acc = __builtin_amdgcn_mfma_f32_16x16x32_f16(xf0, wa0, acc, 0, 0, 0);
            acc = __builtin_amdgcn_mfma_f32_16x16x32_f16(xf1, wa1, acc, 0, 0, 0);
            #pragma unroll
            for (int r = 0; r < 4; ++r)
                hsm[wv][(kg*4 + r)*WPAD + nt*16 + lm] = __float2half(siluf(acc[r]));
        }
        f16x8 ha0 = *reinterpret_cast<const f16x8*>(&hsm[wv][lm*WPAD + kg*8]);
        f16x8 ha1 = *reinterpret_cast<const f16x8*>(&hsm[wv][lm*WPAD + 32 + kg*8]);
        const int orow = base + kg*4;                 // first of 4 consecutive slots
        #pragma unroll 4
        for (int nt = 0; nt < 12; ++nt){
            f16x8 wb0 = *reinterpret_cast<const f16x8*>(&lWb[(nt*16 + lm)*WPAD + kg*8]);
            f16x8 wb1 = *reinterpret_cast<const f16x8*>(&lWb[(nt*16 + lm)*WPAD + 32 + kg*8]);
            f32x4 acc = {0.f,0.f,0.f,0.f};
            acc = __builtin_amdgcn_mfma_f32_16x16x32_f16(ha0, wb0, acc, 0, 0, 0);
            acc = __builtin_amdgcn_mfma_f32_16x16x32_f16(ha1, wb1, acc, 0, 0, 0);
            const int col = nt*16 + lm;
            __half* wr = w_T + (size_t)col*wstride + (orow - rs_slab);
            if (orow + 3 < re_slab){
                union { __half2 h2[2]; uint2 u; } pk;
                pk.h2[0] = __floats2half2_rn(acc[0], acc[1]);
                pk.h2[1] = __floats2half2_rn(acc[2], acc[3]);
                *reinterpret_cast<uint2*>(wr) = pk.u;
            } else {
                #pragma unroll
                for (int r = 0; r < 4; ++r)
                    if (orow + r < re_slab) wr[r] = __float2half(acc[r]);
            }
        }
    }
}

// ---------------- slab aggregation: contiguous w reads (channel-major) ----------------
__global__ __launch_bounds__(384) void agg_slab(
    const int* __restrict__ row_start, int n0, const __half* __restrict__ w_T,
    size_t wstride,
    const int* __restrict__ esrc_s, const float4* __restrict__ eattr_s,
    const __half* __restrict__ f_s, const __half* __restrict__ f_v,
    float* __restrict__ aggs, float* __restrict__ aggv, int N)
{
    const int n = n0 + blockIdx.x;
    if (n >= N) return;
    const int t = threadIdx.x;
    const int rs_slab = row_start[n0];
    const int rs = row_start[n], re = row_start[n+1];
    const size_t N96 = (size_t)N*96;

    int widx, fidx, mode, eac = 0;
    float* outp;
    if (t < 64){ widx = t; fidx = t; mode = 0; eac = 0; outp = aggs + (size_t)n*96 + t; }
    else if (t < 256){ int j = t-64; int c = j>>6; int u = j&63;
        widx = 64+u; fidx = u; mode = 0; eac = 1+c; outp = aggv + (size_t)c*N96 + (size_t)n*96 + u; }
    else if (t < 352){ int j = t-256; int c = j>>5; int u = j&31;
        widx = 128+u; fidx = 3*u+c; mode = 2; outp = aggv + (size_t)c*N96 + (size_t)n*96 + 64+u; }
    else { int u = t-352; widx = 160+u; fidx = 3*u; mode = 1; outp = aggs + (size_t)n*96 + 64+u; }

    __shared__ int   s_src[CHUNK];
    __shared__ float s_ea[4][CHUNK];

    const __half* wrow = w_T + (size_t)widx*wstride;   // contiguous along slots

    float acc = 0.f;
    for (int c0 = rs; c0 < re; c0 += CHUNK){
        const int m = min(CHUNK, re - c0);
        __syncthreads();
        if (t < m){
            s_src[t] = esrc_s[c0 + t];
            float4 ea = eattr_s[c0 + t];
            s_ea[0][t] = ea.x; s_ea[1][t] = ea.y;
            s_ea[2][t] = ea.z; s_ea[3][t] = ea.w;
        }
        __syncthreads();

        const __half* wp = wrow + (c0 - rs_slab);
        if (mode == 0){
            int i = 0;
            for (; i + 8 <= m; i += 8){
                float w8[8], g8[8], e8[8];
                #pragma unroll
                for (int k = 0; k < 8; ++k) w8[k] = __half2float(wp[i+k]);
                #pragma unroll
                for (int k = 0; k < 8; ++k) g8[k] = __half2float(f_s[(size_t)s_src[i+k]*64 + fidx]);
                #pragma unroll
                for (int k = 0; k < 8; ++k) e8[k] = s_ea[eac][i+k];
                #pragma unroll
                for (int k = 0; k < 8; ++k) acc += w8[k]*g8[k]*e8[k];
            }
            for (; i < m; ++i)
                acc += __half2float(wp[i]) * __half2float(f_s[(size_t)s_src[i]*64 + fidx]) * s_ea[eac][i];
        } else if (mode == 2){
            int i = 0;
            for (; i + 8 <= m; i += 8){
                float w8[8], g8[8], e8[8];
                #pragma unroll
                for (int k = 0; k < 8; ++k) w8[k] = __half2float(wp[i+k]);
                #pragma unroll
                for (int k = 0; k < 8; ++k) g8[k] = __half2float(f_v[(size_t)s_src[i+k]*96 + fidx]);
                #pragma unroll
                for (int k = 0; k < 8; ++k) e8[k] = s_ea[0][i+k];
                #pragma unroll
                for (int k = 0; k < 8; ++k) acc += w8[k]*g8[k]*e8[k];
            }
            for (; i < m; ++i)
                acc += __half2float(wp[i]) * __half2float(f_v[(size_t)s_src[i]*96 + fidx]) * s_ea[0][i];
        } else {
            int i = 0;
            for (; i + 4 <= m; i += 4){
                float w4[4], d4[4];
                #pragma unroll
                for (int k = 0; k < 4; ++k) w4[k] = __half2float(wp[i+k]);
                #pragma unroll
                for (int k = 0; k < 4; ++k){
                    const __half* p = f_v + (size_t)s_src[i+k]*96 + fidx;
                    d4[k] = __half2float(p[0])*s_ea[1][i+k] + __half2float(p[1])*s_ea[2][i+k]
                          + __half2float(p[2])*s_ea[3][i+k];
                }
                #pragma unroll
                for (int k = 0; k < 4; ++k) acc += w4[k]*d4[k];
            }
            for (; i < m; ++i){
                const __half* p = f_v + (size_t)s_src[i]*96 + fidx;
                float d = __half2float(p[0])*s_ea[1][i] + __half2float(p[1])*s_ea[2][i]
                        + __half2float(p[2])*s_ea[3][i];
                acc += __half2float(wp[i]) * d;
            }
            acc *= INV_SQRT3;
        }
    }
    *outp = acc;
}

// ---------------- tiled fused post: GEMM (8 nodes/block) + mix ----------------
template<int OS, bool FINAL>
__global__ __launch_bounds__(256) void post_fused(
    const float* __restrict__ aggs, const float* __restrict__ aggv,
    const float* __restrict__ W2s, const float* __restrict__ W2v,
    const float* __restrict__ W3,
    const float* __restrict__ isd, const float* __restrict__ attr,
    const float* __restrict__ sc_s, const float* __restrict__ sc_v,
    float* __restrict__ out_s, float* __restrict__ out_v, int N)
{
    constexpr int TOTC = OS + 1 + 96;
    constexpr int PSTR = 96*8 + 8;
    __shared__ __align__(16) float s_a[4*PSTR];
    __shared__ float s_pre[8][TOTC];

    const int t = threadIdx.x;
    const int n0 = blockIdx.x*8;
    const int nmax = min(8, N - n0);
    const size_t N96 = (size_t)N*96;

    for (int idx = t; idx < 8*96; idx += 256){
        int n = idx/96, k = idx - n*96;
        if (n < nmax) s_a[k*8 + n] = aggs[(size_t)(n0+n)*96 + k];
    }
    for (int idx = t; idx < 3*8*96; idx += 256){
        int p = idx/768, rem = idx - p*768;
        int n = rem/96, k = rem - n*96;
        if (n < nmax) s_a[(1+p)*PSTR + k*8 + n] = aggv[(size_t)p*N96 + (size_t)(n0+n)*96 + k];
    }
    __syncthreads();

    if (t < TOTC){
        const float* bp; int bstr; int plane;
        if (t < OS){ bp = W2s + t; bstr = OS; plane = 0; }
        else if (t == OS){ bp = W3; bstr = 1; plane = 0; }
        else { int q = t - OS - 1; int cv = q>>5, ww = q&31; bp = W2v + ww; bstr = 32; plane = 1+cv; }
        const float* ap = &s_a[plane*PSTR];

        float acc0=0,acc1=0,acc2=0,acc3=0,acc4=0,acc5=0,acc6=0,acc7=0;
        #pragma unroll 4
        for (int k = 0; k < 96; ++k){
            float b = bp[(size_t)k*bstr];
            float4 q0 = *reinterpret_cast<const float4*>(ap + k*8);
            float4 q1 = *reinterpret_cast<const float4*>(ap + k*8 + 4);
            acc0 += q0.x*b; acc1 += q0.y*b; acc2 += q0.z*b; acc3 += q0.w*b;
            acc4 += q1.x*b; acc5 += q1.y*b; acc6 += q1.z*b; acc7 += q1.w*b;
        }
        s_pre[0][t]=acc0; s_pre[1][t]=acc1; s_pre[2][t]=acc2; s_pre[3][t]=acc3;
        s_pre[4][t]=acc4; s_pre[5][t]=acc5; s_pre[6][t]=acc6; s_pre[7][t]=acc7;
    }
    __syncthreads();

    for (int idx = t; idx < nmax*192; idx += 256){
        int n = idx/192, r = idx - n*192;
        int gn = n0 + n;
        float sca = isd[gn]*attr[gn]*INV_SQRT96;
        float ang = 0.1f * s_pre[n][OS] * sca;
        float c_ = cosf(ang), s_ = sinf(ang);
        if (r < OS){
            float hs = c_*sc_s[(size_t)gn*OS + r] + s_*s_pre[n][r]*sca;
            if (FINAL) out_s[(size_t)gn*160 + r] = hs;
            else if (r < 64) out_s[(size_t)gn*64 + r] = siluf(hs);
        } else if (r >= 96){
            int q2 = r - 96;
            int ww = q2/3, c2 = q2 - 3*ww;
            float hv = c_*sc_v[(size_t)gn*96 + q2] + s_*s_pre[n][OS+1 + c2*32 + ww]*sca;
            if (FINAL){
                out_s[(size_t)gn*160 + 64 + q2] = hv;
            } else {
                float hs64 = c_*sc_s[(size_t)gn*OS + 64 + ww] + s_*s_pre[n][64 + ww]*sca;
                float sg = 1.f/(1.f + __expf(-hs64));
                out_v[(size_t)gn*96 + q2] = sg*hv;
            }
        }
    }
}

// ---------------- launch ----------------
extern "C" void kernel_launch(void* const* d_in, const int* in_sizes, int n_in,
                              void* d_out, int out_size, void* d_ws, size_t ws_size,
                              hipStream_t stream)
{
    const float* nf    = (const float*)d_in[0];
    const float* nattr = (const float*)d_in[1];
    const int*   esrc  = (const int*)  d_in[2];
    const int*   edst  = (const int*)  d_in[3];
    const float* eattr = (const float*)d_in[4];
    const float* escal = (const float*)d_in[5];
    const float* p1_sc_s = (const float*)d_in[6];
    const float* p1_sc_v = (const float*)d_in[7];
    const float* p1_l1_s = (const float*)d_in[8];
    const float* p1_l1_v = (const float*)d_in[9];
    const float* p1_fa   = (const float*)d_in[10];
    const float* p1_fb   = (const float*)d_in[11];
    const float* p1_l2_s = (const float*)d_in[12];
    const float* p1_l2_v = (const float*)d_in[13];
    const float* p1_l3   = (const float*)d_in[14];
    const float* p2_sc_s = (const float*)d_in[15];
    const float* p2_sc_v = (const float*)d_in[16];
    const float* p2_l1_s = (const float*)d_in[17];
    const float* p2_l1_v = (const float*)d_in[18];
    const float* p2_fa   = (const float*)d_in[19];
    const float* p2_fb   = (const float*)d_in[20];
    const float* p2_l2_s = (const float*)d_in[21];
    const float* p2_l2_v = (const float*)d_in[22];
    const float* p2_l3   = (const float*)d_in[23];

    const int N = in_sizes[1];
    const int E = in_sizes[2];

    // channel-major w: stride per channel row (slots). Slab slots are
    // deterministic for the fixed input; E/NSLABS + 8192 is a >20-sigma bound.
    const size_t wstride = (size_t)(E/NSLABS + 8192);

    // ---- workspace layout ----
    char* wsb = (char*)d_ws;
    __half* w_T     = (__half*)wsb;   wsb += (size_t)WN*wstride*2;   // ~129 MB
    float4* eattr_s = (float4*)wsb;   wsb += (size_t)E*16;
    __half* Wc1 = (__half*)wsb;       wsb += (size_t)(256*WPAD)*2;
    __half* Wc2 = (__half*)wsb;       wsb += (size_t)(256*WPAD)*2;
    __half* Bs1 = (__half*)wsb;       wsb += (size_t)(160*72)*2;
    __half* Bs2 = (__half*)wsb;       wsb += (size_t)(128*72)*2;
    __half* Bv1 = (__half*)wsb;       wsb += (size_t)(64*40)*2;
    __half* Bv2 = (__half*)wsb;       wsb += (size_t)(64*40)*2;
    __half* fs  = (__half*)wsb;       wsb += (size_t)N*64*2;
    __half* fv  = (__half*)wsb;       wsb += (size_t)N*96*2;
    float* scs  = (float*)wsb;        wsb += (size_t)N*96*4;
    float* scv  = (float*)wsb;        wsb += (size_t)N*96*4;
    float* gs   = (float*)wsb;        wsb += (size_t)N*64*4;
    float* gv   = (float*)wsb;        wsb += (size_t)N*96*4;
    float* aggs = (float*)wsb;        wsb += (size_t)N*96*4;
    float* aggv = (float*)wsb;        wsb += (size_t)N*96*3*4;
    float* isd  = (float*)wsb;        wsb += (size_t)N*4;
    int* cnt       = (int*)wsb;       wsb += (size_t)N*4;
    int* row_start = (int*)wsb;       wsb += (size_t)(N+1)*4;
    int* cursor    = (int*)wsb;       wsb += (size_t)N*4;
    int* perm      = (int*)wsb;       wsb += (size_t)E*4;
    int* esrc_s    = (int*)wsb;       wsb += (size_t)E*4;

    // ---- sort edges by dst + weight prep ----
    hipMemsetAsync(cnt, 0, (size_t)N*4, stream);
    hist_kernel<<<(E+255)/256, 256, 0, stream>>>(edst, cnt, E);
    scan_kernel<<<1, 1024, 0, stream>>>(cnt, row_start, cursor, N, E);
    scatter_kernel<<<(E+255)/256, 256, 0, stream>>>(edst, esrc, (const float4*)eattr,
                                                    cursor, perm, eattr_s, esrc_s, E);
    isd_kernel<<<(N+255)/256, 256, 0, stream>>>(cnt, isd, N);
    wprep<<<(256*WPAD+255)/256, 256, 0, stream>>>(p1_fa, p1_fb, p2_fa, p2_fb, Wc1, Wc2);
    wprep_pre<<<(160*72+128*72+2*64*40+255)/256, 256, 0, stream>>>(
        p1_l1_s, p1_sc_s, p1_l1_v, p1_sc_v,
        p2_l1_s, p2_sc_s, p2_l1_v, p2_sc_v, Bs1, Bs2, Bv1, Bv2);

    const int pre_grid  = (N + 63)/64;
    const int post_grid = (N + 7)/8;
    const int slabN = (N + NSLABS - 1)/NSLABS;
    const int mlp_grid = (E/NSLABS + 63)/64 + 256;

    // ---- conv1 ----
    node_pre_mfma<96><<<pre_grid, 256, 0, stream>>>(nf, 160, nf+64, 160, nattr,
        Bs1, Bv1, fs, scs, fv, scv, N);
    for (int s = 0; s < NSLABS; ++s){
        int n0 = s*slabN; if (n0 >= N) break;
        int n1 = (n0 + slabN < N) ? n0 + slabN : N;
        mlp_gemm_slab<<<mlp_grid, 256, 0, stream>>>(row_start, n0, n1, perm, escal,
                                                    Wc1, w_T, wstride, E);
        agg_slab<<<n1 - n0, 384, 0, stream>>>(row_start, n0, w_T, wstride,
                                              esrc_s, eattr_s, fs, fv, aggs, aggv, N);
    }
    post_fused<96, false><<<post_grid, 256, 0, stream>>>(aggs, aggv,
        p1_l2_s, p1_l2_v, p1_l3, isd, nattr, scs, scv, gs, gv, N);

    // ---- conv2 ----
    node_pre_mfma<64><<<pre_grid, 256, 0, stream>>>(gs, 64, gv, 96, nattr,
        Bs2, Bv2, fs, scs, fv, scv, N);
    for (int s = 0; s < NSLABS; ++s){
        int n0 = s*slabN; if (n0 >= N) break;
        int n1 = (n0 + slabN < N) ? n0 + slabN : N;
        mlp_gemm_slab<<<mlp_grid, 256, 0, stream>>>(row_start, n0, n1, perm, escal,
                                                    Wc2, w_T, wstride, E);
        agg_slab<<<n1 - n0, 384, 0, stream>>>(row_start, n0, w_T, wstride,
                                              esrc_s, eattr_s, fs, fv, aggs, aggv, N);
    }
    post_fused<64, true><<<post_grid, 256, 0, stream>>>(aggs, aggv,
        p2_l2_s, p2_l2_v, p2_l3, isd, nattr, scs, scv, (float*)d_out, nullptr, N);
}

// Round 19
// 528.221 us; speedup vs baseline: 1.4528x; 1.4528x over previous
//
#include <hip/hip_runtime.h>
#include <hip/hip_fp16.h>
#include <cstdint>

// MessagePassing — 2-slab interleaved MFMA edge-MLP (slot-major w) +
// barrier-free streaming aggregation, MFMA node_pre, fp16 f-gathers, 8-node post.
// N=20000, E=320000. CS=64, CV=32, CM=96, WN=192, FCH=64.

#define CS 64
#define CV 32
#define CM 96
#define WN 192
#define FCH 64
#define WPAD 72     // padded K-stride (halfs) for LDS weight tiles
#define NSLABS 2    // slabs per conv

using f16x8 = __attribute__((ext_vector_type(8))) _Float16;
using f32x4 = __attribute__((ext_vector_type(4))) float;

__device__ __forceinline__ float siluf(float x){ return x / (1.f + __expf(-x)); }

constexpr float INV8       = 0.125f;
constexpr float INV_SQRT32 = 0.17677669529663687f;
constexpr float INV_SQRT96 = 0.10206207261596575f;
constexpr float INV_SQRT3  = 0.5773502691896258f;

// ---------------- histogram of edge_dst ----------------
__global__ void hist_kernel(const int* __restrict__ edst, int* __restrict__ cnt, int E){
    int e = blockIdx.x*blockDim.x + threadIdx.x;
    if (e < E) atomicAdd(&cnt[edst[e]], 1);
}

// ---------------- single-block exclusive scan ----------------
__global__ void scan_kernel(const int* __restrict__ cnt, int* __restrict__ row_start,
                            int* __restrict__ cursor, int n, int E){
    __shared__ int part[1024];
    const int t = threadIdx.x;
    const int C = (n + 1023) / 1024;
    int local[32];
    int base = t*C;
    int s = 0;
    for (int j = 0; j < C && j < 32; ++j){
        int idx = base + j;
        int v = (idx < n) ? cnt[idx] : 0;
        local[j] = s; s += v;
    }
    part[t] = s;
    __syncthreads();
    for (int off = 1; off < 1024; off <<= 1){
        int v = (t >= off) ? part[t-off] : 0;
        __syncthreads();
        part[t] += v;
        __syncthreads();
    }
    int pre = (t == 0) ? 0 : part[t-1];
    for (int j = 0; j < C && j < 32; ++j){
        int idx = base + j;
        if (idx < n){ int rs = pre + local[j]; row_start[idx] = rs; cursor[idx] = rs; }
    }
    if (t == 0) row_start[n] = E;
}

// ---------------- scatter: perm + sorted eattr/esrc sidecars ----------------
__global__ void scatter_kernel(const int* __restrict__ edst, const int* __restrict__ esrc,
                               const float4* __restrict__ eattr,
                               int* __restrict__ cursor, int* __restrict__ perm,
                               float4* __restrict__ eattr_s, int* __restrict__ esrc_s, int E){
    int e = blockIdx.x*blockDim.x + threadIdx.x;
    if (e < E){
        int p = atomicAdd(&cursor[edst[e]], 1);
        perm[p] = e; eattr_s[p] = eattr[e]; esrc_s[p] = esrc[e];
    }
}

__global__ void isd_kernel(const int* __restrict__ cnt, float* __restrict__ isd, int n){
    int i = blockIdx.x*blockDim.x + threadIdx.x;
    if (i < n) isd[i] = rsqrtf((float)cnt[i]);
}

// ---------------- weight prep (edge MLP) ----------------
__global__ void wprep(const float* __restrict__ Wfa1, const float* __restrict__ Wfb1,
                      const float* __restrict__ Wfa2, const float* __restrict__ Wfb2,
                      __half* __restrict__ Wc1, __half* __restrict__ Wc2){
    int t = blockIdx.x*blockDim.x + threadIdx.x;
    if (t < 64*WPAD){
        int c = t / WPAD, k = t - c*WPAD;
        float v1 = (k < 64) ? Wfa1[k*64 + c]*INV8 : 0.f;
        float v2 = (k < 64) ? Wfa2[k*64 + c]*INV8 : 0.f;
        Wc1[t] = __float2half(v1); Wc2[t] = __float2half(v2);
    } else if (t < 64*WPAD + 192*WPAD){
        int q = t - 64*WPAD; int o = q / WPAD, k = q - o*WPAD;
        float v1 = (k < 64) ? Wfb1[k*192 + o]*INV8 : 0.f;
        float v2 = (k < 64) ? Wfb2[k*192 + o]*INV8 : 0.f;
        Wc1[t] = __float2half(v1); Wc2[t] = __float2half(v2);
    }
}

// ---------------- weight prep (node_pre) ----------------
__global__ void wprep_pre(
    const float* __restrict__ l1s1, const float* __restrict__ scs1,
    const float* __restrict__ l1v1, const float* __restrict__ scv1,
    const float* __restrict__ l1s2, const float* __restrict__ scs2,
    const float* __restrict__ l1v2, const float* __restrict__ scv2,
    __half* __restrict__ Bs1, __half* __restrict__ Bs2,
    __half* __restrict__ Bv1, __half* __restrict__ Bv2)
{
    int t = blockIdx.x*blockDim.x + threadIdx.x;
    if (t < 160*72){
        int col = t/72, k = t - col*72;
        float v = 0.f;
        if (k < 64) v = (col < 64 ? l1s1[k*64 + col] : scs1[k*96 + (col-64)]) * INV8;
        Bs1[t] = __float2half(v);
    } else if (t < 160*72 + 128*72){
        int q = t - 160*72; int col = q/72, k = q - col*72;
        float v = 0.f;
        if (k < 64) v = (col < 64 ? l1s2[k*64 + col] : scs2[k*64 + (col-64)]) * INV8;
        Bs2[q] = __float2half(v);
    } else if (t < 160*72 + 128*72 + 64*40){
        int q = t - (160*72 + 128*72); int col = q/40, k = q - col*40;
        float v = 0.f;
        if (k < 32) v = (col < 32 ? l1v1[k*32 + col] : scv1[k*32 + (col-32)]) * INV_SQRT32;
        Bv1[q] = __float2half(v);
    } else if (t < 160*72 + 128*72 + 2*64*40){
        int q = t - (160*72 + 128*72 + 64*40); int col = q/40, k = q - col*40;
        float v = 0.f;
        if (k < 32) v = (col < 32 ? l1v2[k*32 + col] : scv2[k*32 + (col-32)]) * INV_SQRT32;
        Bv2[q] = __float2half(v);
    }
}

// ---------------- MFMA node pre-transform: 64 nodes/block ----------------
template<int OS>
__global__ __launch_bounds__(256) void node_pre_mfma(
    const float* __restrict__ s, int ss,
    const float* __restrict__ v, int vs,
    const float* __restrict__ attr,
    const __half* __restrict__ Bs, const __half* __restrict__ Bv,
    __half* __restrict__ f_s, float* __restrict__ sc_s,
    __half* __restrict__ f_v, float* __restrict__ sc_v, int N)
{
    constexpr int SC = 64 + OS;
    __shared__ __align__(16) __half sAh[64*168];
    __shared__ __align__(16) __half lBs[SC*72];
    __shared__ __align__(16) __half lBv[64*40];
    __shared__ float s_at[64];

    const int tid = threadIdx.x;
    const int n0 = blockIdx.x*64;
    const int nmax = min(64, N - n0);

    for (int i = tid; i < (SC*72)/8; i += 256)
        reinterpret_cast<uint4*>(lBs)[i] = reinterpret_cast<const uint4*>(Bs)[i];
    for (int i = tid; i < (64*40)/8; i += 256)
        reinterpret_cast<uint4*>(lBv)[i] = reinterpret_cast<const uint4*>(Bv)[i];
    for (int i = tid; i < 64*64; i += 256){
        int n = i >> 6, k = i & 63;
        float x = (n < nmax) ? s[(size_t)(n0+n)*ss + k] : 0.f;
        sAh[n*168 + k] = __float2half(x);
    }
    for (int i = tid; i < 64*96; i += 256){
        int n = i/96, k = i - n*96;
        float x = (n < nmax) ? v[(size_t)(n0+n)*vs + k] : 0.f;
        sAh[n*168 + 64 + k] = __float2half(x);
    }
    if (tid < 64) s_at[tid] = (tid < nmax) ? attr[n0 + tid] : 0.f;
    __syncthreads();

    const int wv = tid >> 6, l = tid & 63;
    const int lm = l & 15, kg = l >> 4;
    const int rbase = wv*16;
    const int orow = rbase + kg*4;

    f16x8 xf0 = *reinterpret_cast<const f16x8*>(&sAh[(rbase+lm)*168 + kg*8]);
    f16x8 xf1 = *reinterpret_cast<const f16x8*>(&sAh[(rbase+lm)*168 + 32 + kg*8]);
    #pragma unroll
    for (int nt = 0; nt < SC/16; ++nt){
        f16x8 wb0 = *reinterpret_cast<const f16x8*>(&lBs[(nt*16+lm)*72 + kg*8]);
        f16x8 wb1 = *reinterpret_cast<const f16x8*>(&lBs[(nt*16+lm)*72 + 32 + kg*8]);
        f32x4 acc = {0.f,0.f,0.f,0.f};
        acc = __builtin_amdgcn_mfma_f32_16x16x32_f16(xf0, wb0, acc, 0, 0, 0);
        acc = __builtin_amdgcn_mfma_f32_16x16x32_f16(xf1, wb1, acc, 0, 0, 0);
        const int col = nt*16 + lm;
        #pragma unroll
        for (int r = 0; r < 4; ++r){
            int nl = orow + r;
            if (nl < nmax){
                float val = acc[r]*s_at[nl];
                if (col < 64) f_s[(size_t)(n0+nl)*64 + col] = __float2half(val);
                else          sc_s[(size_t)(n0+nl)*OS + (col-64)] = val;
            }
        }
    }

    #pragma unroll
    for (int c = 0; c < 3; ++c){
        f16x8 xa;
        #pragma unroll
        for (int j = 0; j < 8; ++j)
            xa[j] = (_Float16)sAh[(rbase+lm)*168 + 64 + (kg*8+j)*3 + c];
        #pragma unroll
        for (int nt = 0; nt < 4; ++nt){
            f16x8 wb = *reinterpret_cast<const f16x8*>(&lBv[(nt*16+lm)*40 + kg*8]);
            f32x4 acc = {0.f,0.f,0.f,0.f};
            acc = __builtin_amdgcn_mfma_f32_16x16x32_f16(xa, wb, acc, 0, 0, 0);
            const int col = nt*16 + lm;
            #pragma unroll
            for (int r = 0; r < 4; ++r){
                int nl = orow + r;
                if (nl < nmax){
                    float val = acc[r]*s_at[nl];
                    if (col < 32) f_v[(size_t)(n0+nl)*96 + col*3 + c] = __float2half(val);
                    else          sc_v[(size_t)(n0+nl)*96 + (col-32)*3 + c] = val;
                }
            }
        }
    }
}

// ---------------- MFMA edge MLP over one slab (slot-major w) ----------------
__global__ __launch_bounds__(256) void mlp_gemm_slab(
    const int* __restrict__ row_start, int n0, int n1,
    const int* __restrict__ perm, const float* __restrict__ escal,
    const __half* __restrict__ Wc, __half* __restrict__ w_slab, int E)
{
    __shared__ __half lWa[64*WPAD];
    __shared__ __half lWb[192*WPAD];
    __shared__ __half hsm[4][16*WPAD];

    const int rs_slab = row_start[n0];
    const int re_slab = row_start[n1];
    if (rs_slab + (int)blockIdx.x*64 >= re_slab) return;

    const int tid = threadIdx.x;
    {
        const uint4* src4 = reinterpret_cast<const uint4*>(Wc);
        uint4* dA = reinterpret_cast<uint4*>(lWa);
        uint4* dB = reinterpret_cast<uint4*>(lWb);
        for (int i = tid; i < (64*WPAD)/8; i += 256) dA[i] = src4[i];
        for (int i = tid; i < (192*WPAD)/8; i += 256) dB[i] = src4[(64*WPAD)/8 + i];
    }
    __syncthreads();

    const int wv = tid >> 6, l = tid & 63;
    const int lm = l & 15, kg = l >> 4;

    for (int tile = rs_slab + blockIdx.x*64; tile < re_slab; tile += gridDim.x*64){
        const int base = tile + wv*16;
        int slot = base + lm; if (slot >= re_slab) slot = re_slab - 1;
        const int e = perm[slot];
        const float* xp = escal + (size_t)e*64 + kg*8;
        f16x8 xf0, xf1;
        {
            float4 a0 = *reinterpret_cast<const float4*>(xp);
            float4 a1 = *reinterpret_cast<const float4*>(xp + 4);
            float4 b0 = *reinterpret_cast<const float4*>(xp + 32);
            float4 b1 = *reinterpret_cast<const float4*>(xp + 36);
            xf0[0]=(_Float16)a0.x; xf0[1]=(_Float16)a0.y; xf0[2]=(_Float16)a0.z; xf0[3]=(_Float16)a0.w;
            xf0[4]=(_Float16)a1.x; xf0[5]=(_Float16)a1.y; xf0[6]=(_Float16)a1.z; xf0[7]=(_Float16)a1.w;
            xf1[0]=(_Float16)b0.x; xf1[1]=(_Float16)b0.y; xf1[2]=(_Float16)b0.z; xf1[3]=(_Float16)b0.w;
            xf1[4]=(_Float16)b1.x; xf1[5]=(_Float16)b1.y; xf1[6]=(_Float16)b1.z; xf1[7]=(_Float16)b1.w;
        }

        #pragma unroll
        for (int nt = 0; nt < 4; ++nt){
            f16x8 wa0 = *reinterpret_cast<const f16x8*>(&lWa[(nt*16 + lm)*WPAD + kg*8]);
            f16x8 wa1 = *reinterpret_cast<const f16x8*>(&lWa[(nt*16 + lm)*WPAD + 32 + kg*8]);
            f32x4 acc = {0.f,0.f,0.f,0.f};
            acc = __builtin_amdgcn_mfma_f32_16x16x32_f16(xf0, wa0, acc, 0, 0, 0);
            acc = __builtin_amdgcn_mfma_f32_16x16x32_f16(xf1, wa1, acc, 0, 0, 0);
            #pragma unroll
            for (int r = 0; r < 4; ++r)
                hsm[wv][(kg*4 + r)*WPAD + nt*16 + lm] = __float2half(siluf(acc[r]));
        }
        f16x8 ha0 = *reinterpret_cast<const f16x8*>(&hsm[wv][lm*WPAD + kg*8]);
        f16x8 ha1 = *reinterpret_cast<const f16x8*>(&hsm[wv][lm*WPAD + 32 + kg*8]);
        const int orow = base + kg*4;
        #pragma unroll 4
        for (int nt = 0; nt < 12; ++nt){
            f16x8 wb0 = *reinterpret_cast<const f16x8*>(&lWb[(nt*16 + lm)*WPAD + kg*8]);
            f16x8 wb1 = *reinterpret_cast<const f16x8*>(&lWb[(nt*16 + lm)*WPAD + 32 + kg*8]);
            f32x4 acc = {0.f,0.f,0.f,0.f};
            acc = __builtin_amdgcn_mfma_f32_16x16x32_f16(ha0, wb0, acc, 0, 0, 0);
            acc = __builtin_amdgcn_mfma_f32_16x16x32_f16(ha1, wb1, acc, 0, 0, 0);
            #pragma unroll
            for (int r = 0; r < 4; ++r){
                int row = orow + r;
                if (row < re_slab)
                    w_slab[(size_t)(row - rs_slab)*WN + nt*16 + lm] = __float2half(acc[r]);
            }
        }
    }
}

// ---------------- slab aggregation: BARRIER-FREE (uniform src/ea reads) ----------------
__global__ __launch_bounds__(384) void agg_slab(
    const int* __restrict__ row_start, int n0, const __half* __restrict__ w_slab,
    const int* __restrict__ esrc_s, const float* __restrict__ eattr_s4,
    const __half* __restrict__ f_s, const __half* __restrict__ f_v,
    float* __restrict__ aggs, float* __restrict__ aggv, int N)
{
    const int n = n0 + blockIdx.x;
    if (n >= N) return;
    const int t = threadIdx.x;
    const int rs_slab = row_start[n0];
    const int rs = row_start[n], re = row_start[n+1];
    const int cnt = re - rs;
    const size_t N96 = (size_t)N*96;

    int widx, fidx, mode, eac = 0;
    float* outp;
    if (t < 64){ widx = t; fidx = t; mode = 0; eac = 0; outp = aggs + (size_t)n*96 + t; }
    else if (t < 256){ int j = t-64; int c = j>>6; int u = j&63;
        widx = 64+u; fidx = u; mode = 0; eac = 1+c; outp = aggv + (size_t)c*N96 + (size_t)n*96 + u; }
    else if (t < 352){ int j = t-256; int c = j>>5; int u = j&31;
        widx = 128+u; fidx = 3*u+c; mode = 2; outp = aggv + (size_t)c*N96 + (size_t)n*96 + 64+u; }
    else { int u = t-352; widx = 160+u; fidx = 3*u; mode = 1; outp = aggs + (size_t)n*96 + 64+u; }

    const __half* wp = w_slab + (size_t)(rs - rs_slab)*WN + widx;
    const int*  srcp = esrc_s + rs;
    const float* eap = eattr_s4 + (size_t)rs*4;

    float acc = 0.f;
    int i = 0;
    if (mode == 0){
        for (; i + 8 <= cnt; i += 8){
            int   s8[8]; float w8[8], g8[8], e8[8];
            #pragma unroll
            for (int k = 0; k < 8; ++k) s8[k] = srcp[i+k];
            #pragma unroll
            for (int k = 0; k < 8; ++k) e8[k] = eap[(i+k)*4 + eac];
            #pragma unroll
            for (int k = 0; k < 8; ++k) w8[k] = __half2float(wp[(i+k)*WN]);
            #pragma unroll
            for (int k = 0; k < 8; ++k) g8[k] = __half2float(f_s[(size_t)s8[k]*64 + fidx]);
            #pragma unroll
            for (int k = 0; k < 8; ++k) acc += w8[k]*g8[k]*e8[k];
        }
        for (; i < cnt; ++i)
            acc += __half2float(wp[i*WN]) * __half2float(f_s[(size_t)srcp[i]*64 + fidx]) * eap[i*4 + eac];
    } else if (mode == 2){
        for (; i + 8 <= cnt; i += 8){
            int   s8[8]; float w8[8], g8[8], e8[8];
            #pragma unroll
            for (int k = 0; k < 8; ++k) s8[k] = srcp[i+k];
            #pragma unroll
            for (int k = 0; k < 8; ++k) e8[k] = eap[(i+k)*4];
            #pragma unroll
            for (int k = 0; k < 8; ++k) w8[k] = __half2float(wp[(i+k)*WN]);
            #pragma unroll
            for (int k = 0; k < 8; ++k) g8[k] = __half2float(f_v[(size_t)s8[k]*96 + fidx]);
            #pragma unroll
            for (int k = 0; k < 8; ++k) acc += w8[k]*g8[k]*e8[k];
        }
        for (; i < cnt; ++i)
            acc += __half2float(wp[i*WN]) * __half2float(f_v[(size_t)srcp[i]*96 + fidx]) * eap[i*4];
    } else {
        for (; i + 4 <= cnt; i += 4){
            int s4[4]; float w4[4], d4[4];
            #pragma unroll
            for (int k = 0; k < 4; ++k) s4[k] = srcp[i+k];
            #pragma unroll
            for (int k = 0; k < 4; ++k) w4[k] = __half2float(wp[(i+k)*WN]);
            #pragma unroll
            for (int k = 0; k < 4; ++k){
                const __half* p = f_v + (size_t)s4[k]*96 + fidx;
                d4[k] = __half2float(p[0])*eap[(i+k)*4+1] + __half2float(p[1])*eap[(i+k)*4+2]
                      + __half2float(p[2])*eap[(i+k)*4+3];
            }
            #pragma unroll
            for (int k = 0; k < 4; ++k) acc += w4[k]*d4[k];
        }
        for (; i < cnt; ++i){
            const __half* p = f_v + (size_t)srcp[i]*96 + fidx;
            float d = __half2float(p[0])*eap[i*4+1] + __half2float(p[1])*eap[i*4+2]
                    + __half2float(p[2])*eap[i*4+3];
            acc += __half2float(wp[i*WN]) * d;
        }
        acc *= INV_SQRT3;
    }
    *outp = acc;
}

// ---------------- tiled fused post: GEMM (8 nodes/block) + mix ----------------
template<int OS, bool FINAL>
__global__ __launch_bounds__(256) void post_fused(
    const float* __restrict__ aggs, const float* __restrict__ aggv,
    const float* __restrict__ W2s, const float* __restrict__ W2v,
    const float* __restrict__ W3,
    const float* __restrict__ isd, const float* __restrict__ attr,
    const float* __restrict__ sc_s, const float* __restrict__ sc_v,
    float* __restrict__ out_s, float* __restrict__ out_v, int N)
{
    constexpr int TOTC = OS + 1 + 96;
    constexpr int PSTR = 96*8 + 8;
    __shared__ __align__(16) float s_a[4*PSTR];
    __shared__ float s_pre[8][TOTC];

    const int t = threadIdx.x;
    const int n0 = blockIdx.x*8;
    const int nmax = min(8, N - n0);
    const size_t N96 = (size_t)N*96;

    for (int idx = t; idx < 8*96; idx += 256){
        int n = idx/96, k = idx - n*96;
        if (n < nmax) s_a[k*8 + n] = aggs[(size_t)(n0+n)*96 + k];
    }
    for (int idx = t; idx < 3*8*96; idx += 256){
        int p = idx/768, rem = idx - p*768;
        int n = rem/96, k = rem - n*96;
        if (n < nmax) s_a[(1+p)*PSTR + k*8 + n] = aggv[(size_t)p*N96 + (size_t)(n0+n)*96 + k];
    }
    __syncthreads();

    if (t < TOTC){
        const float* bp; int bstr; int plane;
        if (t < OS){ bp = W2s + t; bstr = OS; plane = 0; }
        else if (t == OS){ bp = W3; bstr = 1; plane = 0; }
        else { int q = t - OS - 1; int cv = q>>5, ww = q&31; bp = W2v + ww; bstr = 32; plane = 1+cv; }
        const float* ap = &s_a[plane*PSTR];

        float acc0=0,acc1=0,acc2=0,acc3=0,acc4=0,acc5=0,acc6=0,acc7=0;
        #pragma unroll 4
        for (int k = 0; k < 96; ++k){
            float b = bp[(size_t)k*bstr];
            float4 q0 = *reinterpret_cast<const float4*>(ap + k*8);
            float4 q1 = *reinterpret_cast<const float4*>(ap + k*8 + 4);
            acc0 += q0.x*b; acc1 += q0.y*b; acc2 += q0.z*b; acc3 += q0.w*b;
            acc4 += q1.x*b; acc5 += q1.y*b; acc6 += q1.z*b; acc7 += q1.w*b;
        }
        s_pre[0][t]=acc0; s_pre[1][t]=acc1; s_pre[2][t]=acc2; s_pre[3][t]=acc3;
        s_pre[4][t]=acc4; s_pre[5][t]=acc5; s_pre[6][t]=acc6; s_pre[7][t]=acc7;
    }
    __syncthreads();

    for (int idx = t; idx < nmax*192; idx += 256){
        int n = idx/192, r = idx - n*192;
        int gn = n0 + n;
        float sca = isd[gn]*attr[gn]*INV_SQRT96;
        float ang = 0.1f * s_pre[n][OS] * sca;
        float c_ = cosf(ang), s_ = sinf(ang);
        if (r < OS){
            float hs = c_*sc_s[(size_t)gn*OS + r] + s_*s_pre[n][r]*sca;
            if (FINAL) out_s[(size_t)gn*160 + r] = hs;
            else if (r < 64) out_s[(size_t)gn*64 + r] = siluf(hs);
        } else if (r >= 96){
            int q2 = r - 96;
            int ww = q2/3, c2 = q2 - 3*ww;
            float hv = c_*sc_v[(size_t)gn*96 + q2] + s_*s_pre[n][OS+1 + c2*32 + ww]*sca;
            if (FINAL){
                out_s[(size_t)gn*160 + 64 + q2] = hv;
            } else {
                float hs64 = c_*sc_s[(size_t)gn*OS + 64 + ww] + s_*s_pre[n][64 + ww]*sca;
                float sg = 1.f/(1.f + __expf(-hs64));
                out_v[(size_t)gn*96 + q2] = sg*hv;
            }
        }
    }
}

// ---------------- launch ----------------
extern "C" void kernel_launch(void* const* d_in, const int* in_sizes, int n_in,
                              void* d_out, int out_size, void* d_ws, size_t ws_size,
                              hipStream_t stream)
{
    const float* nf    = (const float*)d_in[0];
    const float* nattr = (const float*)d_in[1];
    const int*   esrc  = (const int*)  d_in[2];
    const int*   edst  = (const int*)  d_in[3];
    const float* eattr = (const float*)d_in[4];
    const float* escal = (const float*)d_in[5];
    const float* p1_sc_s = (const float*)d_in[6];
    const float* p1_sc_v = (const float*)d_in[7];
    const float* p1_l1_s = (const float*)d_in[8];
    const float* p1_l1_v = (const float*)d_in[9];
    const float* p1_fa   = (const float*)d_in[10];
    const float* p1_fb   = (const float*)d_in[11];
    const float* p1_l2_s = (const float*)d_in[12];
    const float* p1_l2_v = (const float*)d_in[13];
    const float* p1_l3   = (const float*)d_in[14];
    const float* p2_sc_s = (const float*)d_in[15];
    const float* p2_sc_v = (const float*)d_in[16];
    const float* p2_l1_s = (const float*)d_in[17];
    const float* p2_l1_v = (const float*)d_in[18];
    const float* p2_fa   = (const float*)d_in[19];
    const float* p2_fb   = (const float*)d_in[20];
    const float* p2_l2_s = (const float*)d_in[21];
    const float* p2_l2_v = (const float*)d_in[22];
    const float* p2_l3   = (const float*)d_in[23];

    const int N = in_sizes[1];
    const int E = in_sizes[2];

    // ---- workspace layout ----
    char* wsb = (char*)d_ws;
    __half* w_s     = (__half*)wsb;   wsb += (size_t)E*WN*2;   // slabs reuse low region
    float4* eattr_s = (float4*)wsb;   wsb += (size_t)E*16;
    __half* Wc1 = (__half*)wsb;       wsb += (size_t)(256*WPAD)*2;
    __half* Wc2 = (__half*)wsb;       wsb += (size_t)(256*WPAD)*2;
    __half* Bs1 = (__half*)wsb;       wsb += (size_t)(160*72)*2;
    __half* Bs2 = (__half*)wsb;       wsb += (size_t)(128*72)*2;
    __half* Bv1 = (__half*)wsb;       wsb += (size_t)(64*40)*2;
    __half* Bv2 = (__half*)wsb;       wsb += (size_t)(64*40)*2;
    __half* fs  = (__half*)wsb;       wsb += (size_t)N*64*2;
    __half* fv  = (__half*)wsb;       wsb += (size_t)N*96*2;
    float* scs  = (float*)wsb;        wsb += (size_t)N*96*4;
    float* scv  = (float*)wsb;        wsb += (size_t)N*96*4;
    float* gs   = (float*)wsb;        wsb += (size_t)N*64*4;
    float* gv   = (float*)wsb;        wsb += (size_t)N*96*4;
    float* aggs = (float*)wsb;        wsb += (size_t)N*96*4;
    float* aggv = (float*)wsb;        wsb += (size_t)N*96*3*4;
    float* isd  = (float*)wsb;        wsb += (size_t)N*4;
    int* cnt       = (int*)wsb;       wsb += (size_t)N*4;
    int* row_start = (int*)wsb;       wsb += (size_t)(N+1)*4;
    int* cursor    = (int*)wsb;       wsb += (size_t)N*4;
    int* perm      = (int*)wsb;       wsb += (size_t)E*4;
    int* esrc_s    = (int*)wsb;       wsb += (size_t)E*4;

    // ---- sort edges by dst + weight prep ----
    hipMemsetAsync(cnt, 0, (size_t)N*4, stream);
    hist_kernel<<<(E+255)/256, 256, 0, stream>>>(edst, cnt, E);
    scan_kernel<<<1, 1024, 0, stream>>>(cnt, row_start, cursor, N, E);
    scatter_kernel<<<(E+255)/256, 256, 0, stream>>>(edst, esrc, (const float4*)eattr,
                                                    cursor, perm, eattr_s, esrc_s, E);
    isd_kernel<<<(N+255)/256, 256, 0, stream>>>(cnt, isd, N);
    wprep<<<(256*WPAD+255)/256, 256, 0, stream>>>(p1_fa, p1_fb, p2_fa, p2_fb, Wc1, Wc2);
    wprep_pre<<<(160*72+128*72+2*64*40+255)/256, 256, 0, stream>>>(
        p1_l1_s, p1_sc_s, p1_l1_v, p1_sc_v,
        p2_l1_s, p2_sc_s, p2_l1_v, p2_sc_v, Bs1, Bs2, Bv1, Bv2);

    const int pre_grid  = (N + 63)/64;
    const int post_grid = (N + 7)/8;
    const int slabN = (N + NSLABS - 1)/NSLABS;
    const int mlp_grid = (E/NSLABS + 63)/64 + 256;

    // ---- conv1 ----
    node_pre_mfma<96><<<pre_grid, 256, 0, stream>>>(nf, 160, nf+64, 160, nattr,
        Bs1, Bv1, fs, scs, fv, scv, N);
    for (int s = 0; s < NSLABS; ++s){
        int n0 = s*slabN; if (n0 >= N) break;
        int n1 = (n0 + slabN < N) ? n0 + slabN : N;
        mlp_gemm_slab<<<mlp_grid, 256, 0, stream>>>(row_start, n0, n1, perm, escal,
                                                    Wc1, w_s, E);
        agg_slab<<<n1 - n0, 384, 0, stream>>>(row_start, n0, w_s,
                                              esrc_s, (const float*)eattr_s, fs, fv, aggs, aggv, N);
    }
    post_fused<96, false><<<post_grid, 256, 0, stream>>>(aggs, aggv,
        p1_l2_s, p1_l2_v, p1_l3, isd, nattr, scs, scv, gs, gv, N);

    // ---- conv2 ----
    node_pre_mfma<64><<<pre_grid, 256, 0, stream>>>(gs, 64, gv, 96, nattr,
        Bs2, Bv2, fs, scs, fv, scv, N);
    for (int s = 0; s < NSLABS; ++s){
        int n0 = s*slabN; if (n0 >= N) break;
        int n1 = (n0 + slabN < N) ? n0 + slabN : N;
        mlp_gemm_slab<<<mlp_grid, 256, 0, stream>>>(row_start, n0, n1, perm, escal,
                                                    Wc2, w_s, E);
        agg_slab<<<n1 - n0, 384, 0, stream>>>(row_start, n0, w_s,
                                              esrc_s, (const float*)eattr_s, fs, fv, aggs, aggv, N);
    }
    post_fused<64, true><<<post_grid, 256, 0, stream>>>(aggs, aggv,
        p2_l2_s, p2_l2_v, p2_l3, isd, nattr, scs, scv, (float*)d_out, nullptr, N);
}

// Round 20
// 475.942 us; speedup vs baseline: 1.6124x; 1.1098x over previous
//
#include <hip/hip_runtime.h>
#include <hip/hip_fp16.h>
#include <cstdint>

// MessagePassing — 2-slab interleaved MFMA edge-MLP (slot-major w, amortized
// weight staging) + LDS-chunk aggregation, MFMA node_pre, fp16 f, 8-node post.
// N=20000, E=320000. CS=64, CV=32, CM=96, WN=192, FCH=64.

#define CS 64
#define CV 32
#define CM 96
#define WN 192
#define FCH 64
#define WPAD 72     // padded K-stride (halfs) for LDS weight tiles
#define CHUNK 64    // src/ea staged per LDS batch in agg
#define NSLABS 2    // slabs per conv

using f16x8 = __attribute__((ext_vector_type(8))) _Float16;
using f32x4 = __attribute__((ext_vector_type(4))) float;

__device__ __forceinline__ float siluf(float x){ return x / (1.f + __expf(-x)); }

constexpr float INV8       = 0.125f;
constexpr float INV_SQRT32 = 0.17677669529663687f;
constexpr float INV_SQRT96 = 0.10206207261596575f;
constexpr float INV_SQRT3  = 0.5773502691896258f;

// ---------------- histogram of edge_dst ----------------
__global__ void hist_kernel(const int* __restrict__ edst, int* __restrict__ cnt, int E){
    int e = blockIdx.x*blockDim.x + threadIdx.x;
    if (e < E) atomicAdd(&cnt[edst[e]], 1);
}

// ---------------- single-block exclusive scan ----------------
__global__ void scan_kernel(const int* __restrict__ cnt, int* __restrict__ row_start,
                            int* __restrict__ cursor, int n, int E){
    __shared__ int part[1024];
    const int t = threadIdx.x;
    const int C = (n + 1023) / 1024;
    int local[32];
    int base = t*C;
    int s = 0;
    for (int j = 0; j < C && j < 32; ++j){
        int idx = base + j;
        int v = (idx < n) ? cnt[idx] : 0;
        local[j] = s; s += v;
    }
    part[t] = s;
    __syncthreads();
    for (int off = 1; off < 1024; off <<= 1){
        int v = (t >= off) ? part[t-off] : 0;
        __syncthreads();
        part[t] += v;
        __syncthreads();
    }
    int pre = (t == 0) ? 0 : part[t-1];
    for (int j = 0; j < C && j < 32; ++j){
        int idx = base + j;
        if (idx < n){ int rs = pre + local[j]; row_start[idx] = rs; cursor[idx] = rs; }
    }
    if (t == 0) row_start[n] = E;
}

// ---------------- scatter: perm + sorted eattr/esrc sidecars ----------------
__global__ void scatter_kernel(const int* __restrict__ edst, const int* __restrict__ esrc,
                               const float4* __restrict__ eattr,
                               int* __restrict__ cursor, int* __restrict__ perm,
                               float4* __restrict__ eattr_s, int* __restrict__ esrc_s, int E){
    int e = blockIdx.x*blockDim.x + threadIdx.x;
    if (e < E){
        int p = atomicAdd(&cursor[edst[e]], 1);
        perm[p] = e; eattr_s[p] = eattr[e]; esrc_s[p] = esrc[e];
    }
}

__global__ void isd_kernel(const int* __restrict__ cnt, float* __restrict__ isd, int n){
    int i = blockIdx.x*blockDim.x + threadIdx.x;
    if (i < n) isd[i] = rsqrtf((float)cnt[i]);
}

// ---------------- weight prep (edge MLP) ----------------
__global__ void wprep(const float* __restrict__ Wfa1, const float* __restrict__ Wfb1,
                      const float* __restrict__ Wfa2, const float* __restrict__ Wfb2,
                      __half* __restrict__ Wc1, __half* __restrict__ Wc2){
    int t = blockIdx.x*blockDim.x + threadIdx.x;
    if (t < 64*WPAD){
        int c = t / WPAD, k = t - c*WPAD;
        float v1 = (k < 64) ? Wfa1[k*64 + c]*INV8 : 0.f;
        float v2 = (k < 64) ? Wfa2[k*64 + c]*INV8 : 0.f;
        Wc1[t] = __float2half(v1); Wc2[t] = __float2half(v2);
    } else if (t < 64*WPAD + 192*WPAD){
        int q = t - 64*WPAD; int o = q / WPAD, k = q - o*WPAD;
        float v1 = (k < 64) ? Wfb1[k*192 + o]*INV8 : 0.f;
        float v2 = (k < 64) ? Wfb2[k*192 + o]*INV8 : 0.f;
        Wc1[t] = __float2half(v1); Wc2[t] = __float2half(v2);
    }
}

// ---------------- weight prep (node_pre) ----------------
__global__ void wprep_pre(
    const float* __restrict__ l1s1, const float* __restrict__ scs1,
    const float* __restrict__ l1v1, const float* __restrict__ scv1,
    const float* __restrict__ l1s2, const float* __restrict__ scs2,
    const float* __restrict__ l1v2, const float* __restrict__ scv2,
    __half* __restrict__ Bs1, __half* __restrict__ Bs2,
    __half* __restrict__ Bv1, __half* __restrict__ Bv2)
{
    int t = blockIdx.x*blockDim.x + threadIdx.x;
    if (t < 160*72){
        int col = t/72, k = t - col*72;
        float v = 0.f;
        if (k < 64) v = (col < 64 ? l1s1[k*64 + col] : scs1[k*96 + (col-64)]) * INV8;
        Bs1[t] = __float2half(v);
    } else if (t < 160*72 + 128*72){
        int q = t - 160*72; int col = q/72, k = q - col*72;
        float v = 0.f;
        if (k < 64) v = (col < 64 ? l1s2[k*64 + col] : scs2[k*64 + (col-64)]) * INV8;
        Bs2[q] = __float2half(v);
    } else if (t < 160*72 + 128*72 + 64*40){
        int q = t - (160*72 + 128*72); int col = q/40, k = q - col*40;
        float v = 0.f;
        if (k < 32) v = (col < 32 ? l1v1[k*32 + col] : scv1[k*32 + (col-32)]) * INV_SQRT32;
        Bv1[q] = __float2half(v);
    } else if (t < 160*72 + 128*72 + 2*64*40){
        int q = t - (160*72 + 128*72 + 64*40); int col = q/40, k = q - col*40;
        float v = 0.f;
        if (k < 32) v = (col < 32 ? l1v2[k*32 + col] : scv2[k*32 + (col-32)]) * INV_SQRT32;
        Bv2[q] = __float2half(v);
    }
}

// ---------------- MFMA node pre-transform: 64 nodes/block ----------------
template<int OS>
__global__ __launch_bounds__(256) void node_pre_mfma(
    const float* __restrict__ s, int ss,
    const float* __restrict__ v, int vs,
    const float* __restrict__ attr,
    const __half* __restrict__ Bs, const __half* __restrict__ Bv,
    __half* __restrict__ f_s, float* __restrict__ sc_s,
    __half* __restrict__ f_v, float* __restrict__ sc_v, int N)
{
    constexpr int SC = 64 + OS;
    __shared__ __align__(16) __half sAh[64*168];
    __shared__ __align__(16) __half lBs[SC*72];
    __shared__ __align__(16) __half lBv[64*40];
    __shared__ float s_at[64];

    const int tid = threadIdx.x;
    const int n0 = blockIdx.x*64;
    const int nmax = min(64, N - n0);

    for (int i = tid; i < (SC*72)/8; i += 256)
        reinterpret_cast<uint4*>(lBs)[i] = reinterpret_cast<const uint4*>(Bs)[i];
    for (int i = tid; i < (64*40)/8; i += 256)
        reinterpret_cast<uint4*>(lBv)[i] = reinterpret_cast<const uint4*>(Bv)[i];
    for (int i = tid; i < 64*64; i += 256){
        int n = i >> 6, k = i & 63;
        float x = (n < nmax) ? s[(size_t)(n0+n)*ss + k] : 0.f;
        sAh[n*168 + k] = __float2half(x);
    }
    for (int i = tid; i < 64*96; i += 256){
        int n = i/96, k = i - n*96;
        float x = (n < nmax) ? v[(size_t)(n0+n)*vs + k] : 0.f;
        sAh[n*168 + 64 + k] = __float2half(x);
    }
    if (tid < 64) s_at[tid] = (tid < nmax) ? attr[n0 + tid] : 0.f;
    __syncthreads();

    const int wv = tid >> 6, l = tid & 63;
    const int lm = l & 15, kg = l >> 4;
    const int rbase = wv*16;
    const int orow = rbase + kg*4;

    f16x8 xf0 = *reinterpret_cast<const f16x8*>(&sAh[(rbase+lm)*168 + kg*8]);
    f16x8 xf1 = *reinterpret_cast<const f16x8*>(&sAh[(rbase+lm)*168 + 32 + kg*8]);
    #pragma unroll
    for (int nt = 0; nt < SC/16; ++nt){
        f16x8 wb0 = *reinterpret_cast<const f16x8*>(&lBs[(nt*16+lm)*72 + kg*8]);
        f16x8 wb1 = *reinterpret_cast<const f16x8*>(&lBs[(nt*16+lm)*72 + 32 + kg*8]);
        f32x4 acc = {0.f,0.f,0.f,0.f};
        acc = __builtin_amdgcn_mfma_f32_16x16x32_f16(xf0, wb0, acc, 0, 0, 0);
        acc = __builtin_amdgcn_mfma_f32_16x16x32_f16(xf1, wb1, acc, 0, 0, 0);
        const int col = nt*16 + lm;
        #pragma unroll
        for (int r = 0; r < 4; ++r){
            int nl = orow + r;
            if (nl < nmax){
                float val = acc[r]*s_at[nl];
                if (col < 64) f_s[(size_t)(n0+nl)*64 + col] = __float2half(val);
                else          sc_s[(size_t)(n0+nl)*OS + (col-64)] = val;
            }
        }
    }

    #pragma unroll
    for (int c = 0; c < 3; ++c){
        f16x8 xa;
        #pragma unroll
        for (int j = 0; j < 8; ++j)
            xa[j] = (_Float16)sAh[(rbase+lm)*168 + 64 + (kg*8+j)*3 + c];
        #pragma unroll
        for (int nt = 0; nt < 4; ++nt){
            f16x8 wb = *reinterpret_cast<const f16x8*>(&lBv[(nt*16+lm)*40 + kg*8]);
            f32x4 acc = {0.f,0.f,0.f,0.f};
            acc = __builtin_amdgcn_mfma_f32_16x16x32_f16(xa, wb, acc, 0, 0, 0);
            const int col = nt*16 + lm;
            #pragma unroll
            for (int r = 0; r < 4; ++r){
                int nl = orow + r;
                if (nl < nmax){
                    float val = acc[r]*s_at[nl];
                    if (col < 32) f_v[(size_t)(n0+nl)*96 + col*3 + c] = __float2half(val);
                    else          sc_v[(size_t)(n0+nl)*96 + (col-32)*3 + c] = val;
                }
            }
        }
    }
}

// ---------------- MFMA edge MLP over one slab (slot-major w, grid-stride) ----------------
__global__ __launch_bounds__(256) void mlp_gemm_slab(
    const int* __restrict__ row_start, int n0, int n1,
    const int* __restrict__ perm, const float* __restrict__ escal,
    const __half* __restrict__ Wc, __half* __restrict__ w_slab, int E)
{
    __shared__ __half lWa[64*WPAD];
    __shared__ __half lWb[192*WPAD];
    __shared__ __half hsm[4][16*WPAD];

    const int rs_slab = row_start[n0];
    const int re_slab = row_start[n1];
    if (rs_slab + (int)blockIdx.x*64 >= re_slab) return;

    const int tid = threadIdx.x;
    {
        const uint4* src4 = reinterpret_cast<const uint4*>(Wc);
        uint4* dA = reinterpret_cast<uint4*>(lWa);
        uint4* dB = reinterpret_cast<uint4*>(lWb);
        for (int i = tid; i < (64*WPAD)/8; i += 256) dA[i] = src4[i];
        for (int i = tid; i < (192*WPAD)/8; i += 256) dB[i] = src4[(64*WPAD)/8 + i];
    }
    __syncthreads();

    const int wv = tid >> 6, l = tid & 63;
    const int lm = l & 15, kg = l >> 4;

    for (int tile = rs_slab + blockIdx.x*64; tile < re_slab; tile += gridDim.x*64){
        const int base = tile + wv*16;
        int slot = base + lm; if (slot >= re_slab) slot = re_slab - 1;
        const int e = perm[slot];
        const float* xp = escal + (size_t)e*64 + kg*8;
        f16x8 xf0, xf1;
        {
            float4 a0 = *reinterpret_cast<const float4*>(xp);
            float4 a1 = *reinterpret_cast<const float4*>(xp + 4);
            float4 b0 = *reinterpret_cast<const float4*>(xp + 32);
            float4 b1 = *reinterpret_cast<const float4*>(xp + 36);
            xf0[0]=(_Float16)a0.x; xf0[1]=(_Float16)a0.y; xf0[2]=(_Float16)a0.z; xf0[3]=(_Float16)a0.w;
            xf0[4]=(_Float16)a1.x; xf0[5]=(_Float16)a1.y; xf0[6]=(_Float16)a1.z; xf0[7]=(_Float16)a1.w;
            xf1[0]=(_Float16)b0.x; xf1[1]=(_Float16)b0.y; xf1[2]=(_Float16)b0.z; xf1[3]=(_Float16)b0.w;
            xf1[4]=(_Float16)b1.x; xf1[5]=(_Float16)b1.y; xf1[6]=(_Float16)b1.z; xf1[7]=(_Float16)b1.w;
        }

        #pragma unroll
        for (int nt = 0; nt < 4; ++nt){
            f16x8 wa0 = *reinterpret_cast<const f16x8*>(&lWa[(nt*16 + lm)*WPAD + kg*8]);
            f16x8 wa1 = *reinterpret_cast<const f16x8*>(&lWa[(nt*16 + lm)*WPAD + 32 + kg*8]);
            f32x4 acc = {0.f,0.f,0.f,0.f};
            acc = __builtin_amdgcn_mfma_f32_16x16x32_f16(xf0, wa0, acc, 0, 0, 0);
            acc = __builtin_amdgcn_mfma_f32_16x16x32_f16(xf1, wa1, acc, 0, 0, 0);
            #pragma unroll
            for (int r = 0; r < 4; ++r)
                hsm[wv][(kg*4 + r)*WPAD + nt*16 + lm] = __float2half(siluf(acc[r]));
        }
        f16x8 ha0 = *reinterpret_cast<const f16x8*>(&hsm[wv][lm*WPAD + kg*8]);
        f16x8 ha1 = *reinterpret_cast<const f16x8*>(&hsm[wv][lm*WPAD + 32 + kg*8]);
        const int orow = base + kg*4;
        #pragma unroll 4
        for (int nt = 0; nt < 12; ++nt){
            f16x8 wb0 = *reinterpret_cast<const f16x8*>(&lWb[(nt*16 + lm)*WPAD + kg*8]);
            f16x8 wb1 = *reinterpret_cast<const f16x8*>(&lWb[(nt*16 + lm)*WPAD + 32 + kg*8]);
            f32x4 acc = {0.f,0.f,0.f,0.f};
            acc = __builtin_amdgcn_mfma_f32_16x16x32_f16(ha0, wb0, acc, 0, 0, 0);
            acc = __builtin_amdgcn_mfma_f32_16x16x32_f16(ha1, wb1, acc, 0, 0, 0);
            #pragma unroll
            for (int r = 0; r < 4; ++r){
                int row = orow + r;
                if (row < re_slab)
                    w_slab[(size_t)(row - rs_slab)*WN + nt*16 + lm] = __float2half(acc[r]);
            }
        }
    }
}

// ---------------- slab aggregation (R16 form: LDS chunk, 8-deep) ----------------
__global__ __launch_bounds__(384) void agg_slab(
    const int* __restrict__ row_start, int n0, const __half* __restrict__ w_slab,
    const int* __restrict__ esrc_s, const float4* __restrict__ eattr_s,
    const __half* __restrict__ f_s, const __half* __restrict__ f_v,
    float* __restrict__ aggs, float* __restrict__ aggv, int N)
{
    const int n = n0 + blockIdx.x;
    if (n >= N) return;
    const int t = threadIdx.x;
    const int rs_slab = row_start[n0];
    const int rs = row_start[n], re = row_start[n+1];
    const size_t N96 = (size_t)N*96;

    int widx, fidx, mode, eac = 0;
    float* outp;
    if (t < 64){ widx = t; fidx = t; mode = 0; eac = 0; outp = aggs + (size_t)n*96 + t; }
    else if (t < 256){ int j = t-64; int c = j>>6; int u = j&63;
        widx = 64+u; fidx = u; mode = 0; eac = 1+c; outp = aggv + (size_t)c*N96 + (size_t)n*96 + u; }
    else if (t < 352){ int j = t-256; int c = j>>5; int u = j&31;
        widx = 128+u; fidx = 3*u+c; mode = 2; outp = aggv + (size_t)c*N96 + (size_t)n*96 + 64+u; }
    else { int u = t-352; widx = 160+u; fidx = 3*u; mode = 1; outp = aggs + (size_t)n*96 + 64+u; }

    __shared__ int   s_src[CHUNK];
    __shared__ float s_ea[4][CHUNK];

    float acc = 0.f;
    for (int c0 = rs; c0 < re; c0 += CHUNK){
        const int m = min(CHUNK, re - c0);
        __syncthreads();
        if (t < m){
            s_src[t] = esrc_s[c0 + t];
            float4 ea = eattr_s[c0 + t];
            s_ea[0][t] = ea.x; s_ea[1][t] = ea.y;
            s_ea[2][t] = ea.z; s_ea[3][t] = ea.w;
        }
        __syncthreads();

        const __half* wp = w_slab + (size_t)(c0 - rs_slab)*WN + widx;
        if (mode == 0){
            int i = 0;
            for (; i + 8 <= m; i += 8){
                float w8[8], g8[8], e8[8];
                #pragma unroll
                for (int k = 0; k < 8; ++k) w8[k] = __half2float(wp[(i+k)*WN]);
                #pragma unroll
                for (int k = 0; k < 8; ++k) g8[k] = __half2float(f_s[(size_t)s_src[i+k]*64 + fidx]);
                #pragma unroll
                for (int k = 0; k < 8; ++k) e8[k] = s_ea[eac][i+k];
                #pragma unroll
                for (int k = 0; k < 8; ++k) acc += w8[k]*g8[k]*e8[k];
            }
            for (; i < m; ++i)
                acc += __half2float(wp[i*WN]) * __half2float(f_s[(size_t)s_src[i]*64 + fidx]) * s_ea[eac][i];
        } else if (mode == 2){
            int i = 0;
            for (; i + 8 <= m; i += 8){
                float w8[8], g8[8], e8[8];
                #pragma unroll
                for (int k = 0; k < 8; ++k) w8[k] = __half2float(wp[(i+k)*WN]);
                #pragma unroll
                for (int k = 0; k < 8; ++k) g8[k] = __half2float(f_v[(size_t)s_src[i+k]*96 + fidx]);
                #pragma unroll
                for (int k = 0; k < 8; ++k) e8[k] = s_ea[0][i+k];
                #pragma unroll
                for (int k = 0; k < 8; ++k) acc += w8[k]*g8[k]*e8[k];
            }
            for (; i < m; ++i)
                acc += __half2float(wp[i*WN]) * __half2float(f_v[(size_t)s_src[i]*96 + fidx]) * s_ea[0][i];
        } else {
            int i = 0;
            for (; i + 4 <= m; i += 4){
                float w4[4], d4[4];
                #pragma unroll
                for (int k = 0; k < 4; ++k) w4[k] = __half2float(wp[(i+k)*WN]);
                #pragma unroll
                for (int k = 0; k < 4; ++k){
                    const __half* p = f_v + (size_t)s_src[i+k]*96 + fidx;
                    d4[k] = __half2float(p[0])*s_ea[1][i+k] + __half2float(p[1])*s_ea[2][i+k]
                          + __half2float(p[2])*s_ea[3][i+k];
                }
                #pragma unroll
                for (int k = 0; k < 4; ++k) acc += w4[k]*d4[k];
            }
            for (; i < m; ++i){
                const __half* p = f_v + (size_t)s_src[i]*96 + fidx;
                float d = __half2float(p[0])*s_ea[1][i] + __half2float(p[1])*s_ea[2][i]
                        + __half2float(p[2])*s_ea[3][i];
                acc += __half2float(wp[i*WN]) * d;
            }
            acc *= INV_SQRT3;
        }
    }
    *outp = acc;
}

// ---------------- tiled fused post: GEMM (8 nodes/block) + mix ----------------
template<int OS, bool FINAL>
__global__ __launch_bounds__(256) void post_fused(
    const float* __restrict__ aggs, const float* __restrict__ aggv,
    const float* __restrict__ W2s, const float* __restrict__ W2v,
    const float* __restrict__ W3,
    const float* __restrict__ isd, const float* __restrict__ attr,
    const float* __restrict__ sc_s, const float* __restrict__ sc_v,
    float* __restrict__ out_s, float* __restrict__ out_v, int N)
{
    constexpr int TOTC = OS + 1 + 96;
    constexpr int PSTR = 96*8 + 8;
    __shared__ __align__(16) float s_a[4*PSTR];
    __shared__ float s_pre[8][TOTC];

    const int t = threadIdx.x;
    const int n0 = blockIdx.x*8;
    const int nmax = min(8, N - n0);
    const size_t N96 = (size_t)N*96;

    for (int idx = t; idx < 8*96; idx += 256){
        int n = idx/96, k = idx - n*96;
        if (n < nmax) s_a[k*8 + n] = aggs[(size_t)(n0+n)*96 + k];
    }
    for (int idx = t; idx < 3*8*96; idx += 256){
        int p = idx/768, rem = idx - p*768;
        int n = rem/96, k = rem - n*96;
        if (n < nmax) s_a[(1+p)*PSTR + k*8 + n] = aggv[(size_t)p*N96 + (size_t)(n0+n)*96 + k];
    }
    __syncthreads();

    if (t < TOTC){
        const float* bp; int bstr; int plane;
        if (t < OS){ bp = W2s + t; bstr = OS; plane = 0; }
        else if (t == OS){ bp = W3; bstr = 1; plane = 0; }
        else { int q = t - OS - 1; int cv = q>>5, ww = q&31; bp = W2v + ww; bstr = 32; plane = 1+cv; }
        const float* ap = &s_a[plane*PSTR];

        float acc0=0,acc1=0,acc2=0,acc3=0,acc4=0,acc5=0,acc6=0,acc7=0;
        #pragma unroll 4
        for (int k = 0; k < 96; ++k){
            float b = bp[(size_t)k*bstr];
            float4 q0 = *reinterpret_cast<const float4*>(ap + k*8);
            float4 q1 = *reinterpret_cast<const float4*>(ap + k*8 + 4);
            acc0 += q0.x*b; acc1 += q0.y*b; acc2 += q0.z*b; acc3 += q0.w*b;
            acc4 += q1.x*b; acc5 += q1.y*b; acc6 += q1.z*b; acc7 += q1.w*b;
        }
        s_pre[0][t]=acc0; s_pre[1][t]=acc1; s_pre[2][t]=acc2; s_pre[3][t]=acc3;
        s_pre[4][t]=acc4; s_pre[5][t]=acc5; s_pre[6][t]=acc6; s_pre[7][t]=acc7;
    }
    __syncthreads();

    for (int idx = t; idx < nmax*192; idx += 256){
        int n = idx/192, r = idx - n*192;
        int gn = n0 + n;
        float sca = isd[gn]*attr[gn]*INV_SQRT96;
        float ang = 0.1f * s_pre[n][OS] * sca;
        float c_ = cosf(ang), s_ = sinf(ang);
        if (r < OS){
            float hs = c_*sc_s[(size_t)gn*OS + r] + s_*s_pre[n][r]*sca;
            if (FINAL) out_s[(size_t)gn*160 + r] = hs;
            else if (r < 64) out_s[(size_t)gn*64 + r] = siluf(hs);
        } else if (r >= 96){
            int q2 = r - 96;
            int ww = q2/3, c2 = q2 - 3*ww;
            float hv = c_*sc_v[(size_t)gn*96 + q2] + s_*s_pre[n][OS+1 + c2*32 + ww]*sca;
            if (FINAL){
                out_s[(size_t)gn*160 + 64 + q2] = hv;
            } else {
                float hs64 = c_*sc_s[(size_t)gn*OS + 64 + ww] + s_*s_pre[n][64 + ww]*sca;
                float sg = 1.f/(1.f + __expf(-hs64));
                out_v[(size_t)gn*96 + q2] = sg*hv;
            }
        }
    }
}

// ---------------- launch ----------------
extern "C" void kernel_launch(void* const* d_in, const int* in_sizes, int n_in,
                              void* d_out, int out_size, void* d_ws, size_t ws_size,
                              hipStream_t stream)
{
    const float* nf    = (const float*)d_in[0];
    const float* nattr = (const float*)d_in[1];
    const int*   esrc  = (const int*)  d_in[2];
    const int*   edst  = (const int*)  d_in[3];
    const float* eattr = (const float*)d_in[4];
    const float* escal = (const float*)d_in[5];
    const float* p1_sc_s = (const float*)d_in[6];
    const float* p1_sc_v = (const float*)d_in[7];
    const float* p1_l1_s = (const float*)d_in[8];
    const float* p1_l1_v = (const float*)d_in[9];
    const float* p1_fa   = (const float*)d_in[10];
    const float* p1_fb   = (const float*)d_in[11];
    const float* p1_l2_s = (const float*)d_in[12];
    const float* p1_l2_v = (const float*)d_in[13];
    const float* p1_l3   = (const float*)d_in[14];
    const float* p2_sc_s = (const float*)d_in[15];
    const float* p2_sc_v = (const float*)d_in[16];
    const float* p2_l1_s = (const float*)d_in[17];
    const float* p2_l1_v = (const float*)d_in[18];
    const float* p2_fa   = (const float*)d_in[19];
    const float* p2_fb   = (const float*)d_in[20];
    const float* p2_l2_s = (const float*)d_in[21];
    const float* p2_l2_v = (const float*)d_in[22];
    const float* p2_l3   = (const float*)d_in[23];

    const int N = in_sizes[1];
    const int E = in_sizes[2];

    // ---- workspace layout ----
    char* wsb = (char*)d_ws;
    __half* w_s     = (__half*)wsb;   wsb += (size_t)E*WN*2;   // slabs reuse low region
    float4* eattr_s = (float4*)wsb;   wsb += (size_t)E*16;
    __half* Wc1 = (__half*)wsb;       wsb += (size_t)(256*WPAD)*2;
    __half* Wc2 = (__half*)wsb;       wsb += (size_t)(256*WPAD)*2;
    __half* Bs1 = (__half*)wsb;       wsb += (size_t)(160*72)*2;
    __half* Bs2 = (__half*)wsb;       wsb += (size_t)(128*72)*2;
    __half* Bv1 = (__half*)wsb;       wsb += (size_t)(64*40)*2;
    __half* Bv2 = (__half*)wsb;       wsb += (size_t)(64*40)*2;
    __half* fs  = (__half*)wsb;       wsb += (size_t)N*64*2;
    __half* fv  = (__half*)wsb;       wsb += (size_t)N*96*2;
    float* scs  = (float*)wsb;        wsb += (size_t)N*96*4;
    float* scv  = (float*)wsb;        wsb += (size_t)N*96*4;
    float* gs   = (float*)wsb;        wsb += (size_t)N*64*4;
    float* gv   = (float*)wsb;        wsb += (size_t)N*96*4;
    float* aggs = (float*)wsb;        wsb += (size_t)N*96*4;
    float* aggv = (float*)wsb;        wsb += (size_t)N*96*3*4;
    float* isd  = (float*)wsb;        wsb += (size_t)N*4;
    int* cnt       = (int*)wsb;       wsb += (size_t)N*4;
    int* row_start = (int*)wsb;       wsb += (size_t)(N+1)*4;
    int* cursor    = (int*)wsb;       wsb += (size_t)N*4;
    int* perm      = (int*)wsb;       wsb += (size_t)E*4;
    int* esrc_s    = (int*)wsb;       wsb += (size_t)E*4;

    // ---- sort edges by dst + weight prep ----
    hipMemsetAsync(cnt, 0, (size_t)N*4, stream);
    hist_kernel<<<(E+255)/256, 256, 0, stream>>>(edst, cnt, E);
    scan_kernel<<<1, 1024, 0, stream>>>(cnt, row_start, cursor, N, E);
    scatter_kernel<<<(E+255)/256, 256, 0, stream>>>(edst, esrc, (const float4*)eattr,
                                                    cursor, perm, eattr_s, esrc_s, E);
    isd_kernel<<<(N+255)/256, 256, 0, stream>>>(cnt, isd, N);
    wprep<<<(256*WPAD+255)/256, 256, 0, stream>>>(p1_fa, p1_fb, p2_fa, p2_fb, Wc1, Wc2);
    wprep_pre<<<(160*72+128*72+2*64*40+255)/256, 256, 0, stream>>>(
        p1_l1_s, p1_sc_s, p1_l1_v, p1_sc_v,
        p2_l1_s, p2_sc_s, p2_l1_v, p2_sc_v, Bs1, Bs2, Bv1, Bv2);

    const int pre_grid  = (N + 63)/64;
    const int post_grid = (N + 7)/8;
    const int slabN = (N + NSLABS - 1)/NSLABS;
    const int mlp_grid = 768;   // grid-stride: ~3-4 tiles/block, amortizes weight staging

    // ---- conv1 ----
    node_pre_mfma<96><<<pre_grid, 256, 0, stream>>>(nf, 160, nf+64, 160, nattr,
        Bs1, Bv1, fs, scs, fv, scv, N);
    for (int s = 0; s < NSLABS; ++s){
        int n0 = s*slabN; if (n0 >= N) break;
        int n1 = (n0 + slabN < N) ? n0 + slabN : N;
        mlp_gemm_slab<<<mlp_grid, 256, 0, stream>>>(row_start, n0, n1, perm, escal,
                                                    Wc1, w_s, E);
        agg_slab<<<n1 - n0, 384, 0, stream>>>(row_start, n0, w_s,
                                              esrc_s, eattr_s, fs, fv, aggs, aggv, N);
    }
    post_fused<96, false><<<post_grid, 256, 0, stream>>>(aggs, aggv,
        p1_l2_s, p1_l2_v, p1_l3, isd, nattr, scs, scv, gs, gv, N);

    // ---- conv2 ----
    node_pre_mfma<64><<<pre_grid, 256, 0, stream>>>(gs, 64, gv, 96, nattr,
        Bs2, Bv2, fs, scs, fv, scv, N);
    for (int s = 0; s < NSLABS; ++s){
        int n0 = s*slabN; if (n0 >= N) break;
        int n1 = (n0 + slabN < N) ? n0 + slabN : N;
        mlp_gemm_slab<<<mlp_grid, 256, 0, stream>>>(row_start, n0, n1, perm, escal,
                                                    Wc2, w_s, E);
        agg_slab<<<n1 - n0, 384, 0, stream>>>(row_start, n0, w_s,
                                              esrc_s, eattr_s, fs, fv, aggs, aggv, N);
    }
    post_fused<64, true><<<post_grid, 256, 0, stream>>>(aggs, aggv,
        p2_l2_s, p2_l2_v, p2_l3, isd, nattr, scs, scv, (float*)d_out, nullptr, N);
}

// Round 21
// 380.689 us; speedup vs baseline: 2.0159x; 1.2502x over previous
//
#include <hip/hip_runtime.h>
#include <hip/hip_fp16.h>
#include <cstdint>

// MessagePassing — 2-slab interleaved MFMA edge-MLP (slot-major w, amortized
// weight staging) + dedup-role aggregation, MFMA node_pre, fp16 f, 8-node post.
// N=20000, E=320000. CS=64, CV=32, CM=96, WN=192, FCH=64.

#define CS 64
#define CV 32
#define CM 96
#define WN 192
#define FCH 64
#define WPAD 72     // padded K-stride (halfs) for LDS weight tiles
#define CHUNK 64    // src/ea staged per LDS batch in agg
#define NSLABS 2    // slabs per conv

using f16x8 = __attribute__((ext_vector_type(8))) _Float16;
using f32x4 = __attribute__((ext_vector_type(4))) float;

__device__ __forceinline__ float siluf(float x){ return x / (1.f + __expf(-x)); }

constexpr float INV8       = 0.125f;
constexpr float INV_SQRT32 = 0.17677669529663687f;
constexpr float INV_SQRT96 = 0.10206207261596575f;
constexpr float INV_SQRT3  = 0.5773502691896258f;

// ---------------- histogram of edge_dst ----------------
__global__ void hist_kernel(const int* __restrict__ edst, int* __restrict__ cnt, int E){
    int e = blockIdx.x*blockDim.x + threadIdx.x;
    if (e < E) atomicAdd(&cnt[edst[e]], 1);
}

// ---------------- single-block exclusive scan ----------------
__global__ void scan_kernel(const int* __restrict__ cnt, int* __restrict__ row_start,
                            int* __restrict__ cursor, int n, int E){
    __shared__ int part[1024];
    const int t = threadIdx.x;
    const int C = (n + 1023) / 1024;
    int local[32];
    int base = t*C;
    int s = 0;
    for (int j = 0; j < C && j < 32; ++j){
        int idx = base + j;
        int v = (idx < n) ? cnt[idx] : 0;
        local[j] = s; s += v;
    }
    part[t] = s;
    __syncthreads();
    for (int off = 1; off < 1024; off <<= 1){
        int v = (t >= off) ? part[t-off] : 0;
        __syncthreads();
        part[t] += v;
        __syncthreads();
    }
    int pre = (t == 0) ? 0 : part[t-1];
    for (int j = 0; j < C && j < 32; ++j){
        int idx = base + j;
        if (idx < n){ int rs = pre + local[j]; row_start[idx] = rs; cursor[idx] = rs; }
    }
    if (t == 0) row_start[n] = E;
}

// ---------------- scatter: perm + sorted eattr/esrc sidecars ----------------
__global__ void scatter_kernel(const int* __restrict__ edst, const int* __restrict__ esrc,
                               const float4* __restrict__ eattr,
                               int* __restrict__ cursor, int* __restrict__ perm,
                               float4* __restrict__ eattr_s, int* __restrict__ esrc_s, int E){
    int e = blockIdx.x*blockDim.x + threadIdx.x;
    if (e < E){
        int p = atomicAdd(&cursor[edst[e]], 1);
        perm[p] = e; eattr_s[p] = eattr[e]; esrc_s[p] = esrc[e];
    }
}

__global__ void isd_kernel(const int* __restrict__ cnt, float* __restrict__ isd, int n){
    int i = blockIdx.x*blockDim.x + threadIdx.x;
    if (i < n) isd[i] = rsqrtf((float)cnt[i]);
}

// ---------------- weight prep (edge MLP) ----------------
__global__ void wprep(const float* __restrict__ Wfa1, const float* __restrict__ Wfb1,
                      const float* __restrict__ Wfa2, const float* __restrict__ Wfb2,
                      __half* __restrict__ Wc1, __half* __restrict__ Wc2){
    int t = blockIdx.x*blockDim.x + threadIdx.x;
    if (t < 64*WPAD){
        int c = t / WPAD, k = t - c*WPAD;
        float v1 = (k < 64) ? Wfa1[k*64 + c]*INV8 : 0.f;
        float v2 = (k < 64) ? Wfa2[k*64 + c]*INV8 : 0.f;
        Wc1[t] = __float2half(v1); Wc2[t] = __float2half(v2);
    } else if (t < 64*WPAD + 192*WPAD){
        int q = t - 64*WPAD; int o = q / WPAD, k = q - o*WPAD;
        float v1 = (k < 64) ? Wfb1[k*192 + o]*INV8 : 0.f;
        float v2 = (k < 64) ? Wfb2[k*192 + o]*INV8 : 0.f;
        Wc1[t] = __float2half(v1); Wc2[t] = __float2half(v2);
    }
}

// ---------------- weight prep (node_pre) ----------------
__global__ void wprep_pre(
    const float* __restrict__ l1s1, const float* __restrict__ scs1,
    const float* __restrict__ l1v1, const float* __restrict__ scv1,
    const float* __restrict__ l1s2, const float* __restrict__ scs2,
    const float* __restrict__ l1v2, const float* __restrict__ scv2,
    __half* __restrict__ Bs1, __half* __restrict__ Bs2,
    __half* __restrict__ Bv1, __half* __restrict__ Bv2)
{
    int t = blockIdx.x*blockDim.x + threadIdx.x;
    if (t < 160*72){
        int col = t/72, k = t - col*72;
        float v = 0.f;
        if (k < 64) v = (col < 64 ? l1s1[k*64 + col] : scs1[k*96 + (col-64)]) * INV8;
        Bs1[t] = __float2half(v);
    } else if (t < 160*72 + 128*72){
        int q = t - 160*72; int col = q/72, k = q - col*72;
        float v = 0.f;
        if (k < 64) v = (col < 64 ? l1s2[k*64 + col] : scs2[k*64 + (col-64)]) * INV8;
        Bs2[q] = __float2half(v);
    } else if (t < 160*72 + 128*72 + 64*40){
        int q = t - (160*72 + 128*72); int col = q/40, k = q - col*40;
        float v = 0.f;
        if (k < 32) v = (col < 32 ? l1v1[k*32 + col] : scv1[k*32 + (col-32)]) * INV_SQRT32;
        Bv1[q] = __float2half(v);
    } else if (t < 160*72 + 128*72 + 2*64*40){
        int q = t - (160*72 + 128*72 + 64*40); int col = q/40, k = q - col*40;
        float v = 0.f;
        if (k < 32) v = (col < 32 ? l1v2[k*32 + col] : scv2[k*32 + (col-32)]) * INV_SQRT32;
        Bv2[q] = __float2half(v);
    }
}

// ---------------- MFMA node pre-transform: 64 nodes/block ----------------
template<int OS>
__global__ __launch_bounds__(256) void node_pre_mfma(
    const float* __restrict__ s, int ss,
    const float* __restrict__ v, int vs,
    const float* __restrict__ attr,
    const __half* __restrict__ Bs, const __half* __restrict__ Bv,
    __half* __restrict__ f_s, float* __restrict__ sc_s,
    __half* __restrict__ f_v, float* __restrict__ sc_v, int N)
{
    constexpr int SC = 64 + OS;
    __shared__ __align__(16) __half sAh[64*168];
    __shared__ __align__(16) __half lBs[SC*72];
    __shared__ __align__(16) __half lBv[64*40];
    __shared__ float s_at[64];

    const int tid = threadIdx.x;
    const int n0 = blockIdx.x*64;
    const int nmax = min(64, N - n0);

    for (int i = tid; i < (SC*72)/8; i += 256)
        reinterpret_cast<uint4*>(lBs)[i] = reinterpret_cast<const uint4*>(Bs)[i];
    for (int i = tid; i < (64*40)/8; i += 256)
        reinterpret_cast<uint4*>(lBv)[i] = reinterpret_cast<const uint4*>(Bv)[i];
    for (int i = tid; i < 64*64; i += 256){
        int n = i >> 6, k = i & 63;
        float x = (n < nmax) ? s[(size_t)(n0+n)*ss + k] : 0.f;
        sAh[n*168 + k] = __float2half(x);
    }
    for (int i = tid; i < 64*96; i += 256){
        int n = i/96, k = i - n*96;
        float x = (n < nmax) ? v[(size_t)(n0+n)*vs + k] : 0.f;
        sAh[n*168 + 64 + k] = __float2half(x);
    }
    if (tid < 64) s_at[tid] = (tid < nmax) ? attr[n0 + tid] : 0.f;
    __syncthreads();

    const int wv = tid >> 6, l = tid & 63;
    const int lm = l & 15, kg = l >> 4;
    const int rbase = wv*16;
    const int orow = rbase + kg*4;

    f16x8 xf0 = *reinterpret_cast<const f16x8*>(&sAh[(rbase+lm)*168 + kg*8]);
    f16x8 xf1 = *reinterpret_cast<const f16x8*>(&sAh[(rbase+lm)*168 + 32 + kg*8]);
    #pragma unroll
    for (int nt = 0; nt < SC/16; ++nt){
        f16x8 wb0 = *reinterpret_cast<const f16x8*>(&lBs[(nt*16+lm)*72 + kg*8]);
        f16x8 wb1 = *reinterpret_cast<const f16x8*>(&lBs[(nt*16+lm)*72 + 32 + kg*8]);
        f32x4 acc = {0.f,0.f,0.f,0.f};
        acc = __builtin_amdgcn_mfma_f32_16x16x32_f16(xf0, wb0, acc, 0, 0, 0);
        acc = __builtin_amdgcn_mfma_f32_16x16x32_f16(xf1, wb1, acc, 0, 0, 0);
        const int col = nt*16 + lm;
        #pragma unroll
        for (int r = 0; r < 4; ++r){
            int nl = orow + r;
            if (nl < nmax){
                float val = acc[r]*s_at[nl];
                if (col < 64) f_s[(size_t)(n0+nl)*64 + col] = __float2half(val);
                else          sc_s[(size_t)(n0+nl)*OS + (col-64)] = val;
            }
        }
    }

    #pragma unroll
    for (int c = 0; c < 3; ++c){
        f16x8 xa;
        #pragma unroll
        for (int j = 0; j < 8; ++j)
            xa[j] = (_Float16)sAh[(rbase+lm)*168 + 64 + (kg*8+j)*3 + c];
        #pragma unroll
        for (int nt = 0; nt < 4; ++nt){
            f16x8 wb = *reinterpret_cast<const f16x8*>(&lBv[(nt*16+lm)*40 + kg*8]);
            f32x4 acc = {0.f,0.f,0.f,0.f};
            acc = __builtin_amdgcn_mfma_f32_16x16x32_f16(xa, wb, acc, 0, 0, 0);
            const int col = nt*16 + lm;
            #pragma unroll
            for (int r = 0; r < 4; ++r){
                int nl = orow + r;
                if (nl < nmax){
                    float val = acc[r]*s_at[nl];
                    if (col < 32) f_v[(size_t)(n0+nl)*96 + col*3 + c] = __float2half(val);
                    else          sc_v[(size_t)(n0+nl)*96 + (col-32)*3 + c] = val;
                }
            }
        }
    }
}

// ---------------- MFMA edge MLP over one slab (slot-major w, grid-stride) ----------------
__global__ __launch_bounds__(256) void mlp_gemm_slab(
    const int* __restrict__ row_start, int n0, int n1,
    const int* __restrict__ perm, const float* __restrict__ escal,
    const __half* __restrict__ Wc, __half* __restrict__ w_slab, int E)
{
    __shared__ __half lWa[64*WPAD];
    __shared__ __half lWb[192*WPAD];
    __shared__ __half hsm[4][16*WPAD];

    const int rs_slab = row_start[n0];
    const int re_slab = row_start[n1];
    if (rs_slab + (int)blockIdx.x*64 >= re_slab) return;

    const int tid = threadIdx.x;
    {
        const uint4* src4 = reinterpret_cast<const uint4*>(Wc);
        uint4* dA = reinterpret_cast<uint4*>(lWa);
        uint4* dB = reinterpret_cast<uint4*>(lWb);
        for (int i = tid; i < (64*WPAD)/8; i += 256) dA[i] = src4[i];
        for (int i = tid; i < (192*WPAD)/8; i += 256) dB[i] = src4[(64*WPAD)/8 + i];
    }
    __syncthreads();

    const int wv = tid >> 6, l = tid & 63;
    const int lm = l & 15, kg = l >> 4;

    for (int tile = rs_slab + blockIdx.x*64; tile < re_slab; tile += gridDim.x*64){
        const int base = tile + wv*16;
        int slot = base + lm; if (slot >= re_slab) slot = re_slab - 1;
        const int e = perm[slot];
        const float* xp = escal + (size_t)e*64 + kg*8;
        f16x8 xf0, xf1;
        {
            float4 a0 = *reinterpret_cast<const float4*>(xp);
            float4 a1 = *reinterpret_cast<const float4*>(xp + 4);
            float4 b0 = *reinterpret_cast<const float4*>(xp + 32);
            float4 b1 = *reinterpret_cast<const float4*>(xp + 36);
            xf0[0]=(_Float16)a0.x; xf0[1]=(_Float16)a0.y; xf0[2]=(_Float16)a0.z; xf0[3]=(_Float16)a0.w;
            xf0[4]=(_Float16)a1.x; xf0[5]=(_Float16)a1.y; xf0[6]=(_Float16)a1.z; xf0[7]=(_Float16)a1.w;
            xf1[0]=(_Float16)b0.x; xf1[1]=(_Float16)b0.y; xf1[2]=(_Float16)b0.z; xf1[3]=(_Float16)b0.w;
            xf1[4]=(_Float16)b1.x; xf1[5]=(_Float16)b1.y; xf1[6]=(_Float16)b1.z; xf1[7]=(_Float16)b1.w;
        }

        #pragma unroll
        for (int nt = 0; nt < 4; ++nt){
            f16x8 wa0 = *reinterpret_cast<const f16x8*>(&lWa[(nt*16 + lm)*WPAD + kg*8]);
            f16x8 wa1 = *reinterpret_cast<const f16x8*>(&lWa[(nt*16 + lm)*WPAD + 32 + kg*8]);
            f32x4 acc = {0.f,0.f,0.f,0.f};
            acc = __builtin_amdgcn_mfma_f32_16x16x32_f16(xf0, wa0, acc, 0, 0, 0);
            acc = __builtin_amdgcn_mfma_f32_16x16x32_f16(xf1, wa1, acc, 0, 0, 0);
            #pragma unroll
            for (int r = 0; r < 4; ++r)
                hsm[wv][(kg*4 + r)*WPAD + nt*16 + lm] = __float2half(siluf(acc[r]));
        }
        f16x8 ha0 = *reinterpret_cast<const f16x8*>(&hsm[wv][lm*WPAD + kg*8]);
        f16x8 ha1 = *reinterpret_cast<const f16x8*>(&hsm[wv][lm*WPAD + 32 + kg*8]);
        const int orow = base + kg*4;
        #pragma unroll 4
        for (int nt = 0; nt < 12; ++nt){
            f16x8 wb0 = *reinterpret_cast<const f16x8*>(&lWb[(nt*16 + lm)*WPAD + kg*8]);
            f16x8 wb1 = *reinterpret_cast<const f16x8*>(&lWb[(nt*16 + lm)*WPAD + 32 + kg*8]);
            f32x4 acc = {0.f,0.f,0.f,0.f};
            acc = __builtin_amdgcn_mfma_f32_16x16x32_f16(ha0, wb0, acc, 0, 0, 0);
            acc = __builtin_amdgcn_mfma_f32_16x16x32_f16(ha1, wb1, acc, 0, 0, 0);
            #pragma unroll
            for (int r = 0; r < 4; ++r){
                int row = orow + r;
                if (row < re_slab)
                    w_slab[(size_t)(row - rs_slab)*WN + nt*16 + lm] = __float2half(acc[r]);
            }
        }
    }
}

// ---------------- slab aggregation: dedup roles, 128 threads (96 active) ----------------
// Scalar t in [0,64): acc a0=A(aggs[t]); a1..a3=C planes (aggv[c][n][t]).
//   per edge: w[t], w[64+t], fs[t] -> 1 f load + 2 w loads.
// Vector u=t-64 in [0,32): acc a0..a2=D planes (aggv[c][n][64+u]); a3=B (aggs[64+u]).
//   per edge: w[128+u], w[160+u], fv[3u..3u+2] -> 3 half loads + 2 w loads.
__global__ __launch_bounds__(128) void agg_slab(
    const int* __restrict__ row_start, int n0, const __half* __restrict__ w_slab,
    const int* __restrict__ esrc_s, const float4* __restrict__ eattr_s,
    const __half* __restrict__ f_s, const __half* __restrict__ f_v,
    float* __restrict__ aggs, float* __restrict__ aggv, int N)
{
    const int n = n0 + blockIdx.x;
    if (n >= N) return;
    const int t = threadIdx.x;
    const int rs_slab = row_start[n0];
    const int rs = row_start[n], re = row_start[n+1];
    const size_t N96 = (size_t)N*96;

    __shared__ int   s_src[CHUNK];
    __shared__ float s_ea[4][CHUNK];

    const bool isScalar = (t < 64);
    const int u = t - 64;

    float a0 = 0.f, a1 = 0.f, a2 = 0.f, a3 = 0.f;

    for (int c0 = rs; c0 < re; c0 += CHUNK){
        const int m = min(CHUNK, re - c0);
        __syncthreads();
        if (t < m){
            s_src[t] = esrc_s[c0 + t];
            float4 ea = eattr_s[c0 + t];
            s_ea[0][t] = ea.x; s_ea[1][t] = ea.y;
            s_ea[2][t] = ea.z; s_ea[3][t] = ea.w;
        }
        __syncthreads();

        const __half* wp = w_slab + (size_t)(c0 - rs_slab)*WN;

        if (isScalar){
            int i = 0;
            for (; i + 4 <= m; i += 4){
                float w0[4], w1[4], g[4];
                int   s4[4];
                #pragma unroll
                for (int k = 0; k < 4; ++k) s4[k] = s_src[i+k];
                #pragma unroll
                for (int k = 0; k < 4; ++k) w0[k] = __half2float(wp[(size_t)(i+k)*WN + t]);
                #pragma unroll
                for (int k = 0; k < 4; ++k) w1[k] = __half2float(wp[(size_t)(i+k)*WN + 64 + t]);
                #pragma unroll
                for (int k = 0; k < 4; ++k) g[k]  = __half2float(f_s[(size_t)s4[k]*64 + t]);
                #pragma unroll
                for (int k = 0; k < 4; ++k){
                    float wg = w1[k]*g[k];
                    a0 += w0[k]*g[k]*s_ea[0][i+k];
                    a1 += wg*s_ea[1][i+k];
                    a2 += wg*s_ea[2][i+k];
                    a3 += wg*s_ea[3][i+k];
                }
            }
            for (; i < m; ++i){
                int src = s_src[i];
                float w0 = __half2float(wp[(size_t)i*WN + t]);
                float w1 = __half2float(wp[(size_t)i*WN + 64 + t]);
                float g  = __half2float(f_s[(size_t)src*64 + t]);
                float wg = w1*g;
                a0 += w0*g*s_ea[0][i];
                a1 += wg*s_ea[1][i];
                a2 += wg*s_ea[2][i];
                a3 += wg*s_ea[3][i];
            }
        } else if (u < 32){
            int i = 0;
            for (; i + 4 <= m; i += 4){
                float w2[4], w3[4], f0[4], f1[4], f2[4];
                int s4[4];
                #pragma unroll
                for (int k = 0; k < 4; ++k) s4[k] = s_src[i+k];
                #pragma unroll
                for (int k = 0; k < 4; ++k) w2[k] = __half2float(wp[(size_t)(i+k)*WN + 128 + u]);
                #pragma unroll
                for (int k = 0; k < 4; ++k) w3[k] = __half2float(wp[(size_t)(i+k)*WN + 160 + u]);
                #pragma unroll
                for (int k = 0; k < 4; ++k){
                    const __half* p = f_v + (size_t)s4[k]*96 + 3*u;
                    f0[k] = __half2float(p[0]); f1[k] = __half2float(p[1]); f2[k] = __half2float(p[2]);
                }
                #pragma unroll
                for (int k = 0; k < 4; ++k){
                    float eax = s_ea[0][i+k];
                    float w2e = w2[k]*eax;
                    a0 += w2e*f0[k];
                    a1 += w2e*f1[k];
                    a2 += w2e*f2[k];
                    a3 += w3[k]*(f0[k]*s_ea[1][i+k] + f1[k]*s_ea[2][i+k] + f2[k]*s_ea[3][i+k]);
                }
            }
            for (; i < m; ++i){
                int src = s_src[i];
                float w2 = __half2float(wp[(size_t)i*WN + 128 + u]);
                float w3 = __half2float(wp[(size_t)i*WN + 160 + u]);
                const __half* p = f_v + (size_t)src*96 + 3*u;
                float f0 = __half2float(p[0]), f1 = __half2float(p[1]), f2 = __half2float(p[2]);
                float w2e = w2*s_ea[0][i];
                a0 += w2e*f0; a1 += w2e*f1; a2 += w2e*f2;
                a3 += w3*(f0*s_ea[1][i] + f1*s_ea[2][i] + f2*s_ea[3][i]);
            }
        }
    }

    // write-out
    if (isScalar){
        aggs[(size_t)n*96 + t] = a0;
        aggv[(size_t)0*N96 + (size_t)n*96 + t] = a1;
        aggv[(size_t)1*N96 + (size_t)n*96 + t] = a2;
        aggv[(size_t)2*N96 + (size_t)n*96 + t] = a3;
    } else if (u < 32){
        aggv[(size_t)0*N96 + (size_t)n*96 + 64 + u] = a0;
        aggv[(size_t)1*N96 + (size_t)n*96 + 64 + u] = a1;
        aggv[(size_t)2*N96 + (size_t)n*96 + 64 + u] = a2;
        aggs[(size_t)n*96 + 64 + u] = a3*INV_SQRT3;
    }
}

// ---------------- tiled fused post: GEMM (8 nodes/block) + mix ----------------
template<int OS, bool FINAL>
__global__ __launch_bounds__(256) void post_fused(
    const float* __restrict__ aggs, const float* __restrict__ aggv,
    const float* __restrict__ W2s, const float* __restrict__ W2v,
    const float* __restrict__ W3,
    const float* __restrict__ isd, const float* __restrict__ attr,
    const float* __restrict__ sc_s, const float* __restrict__ sc_v,
    float* __restrict__ out_s, float* __restrict__ out_v, int N)
{
    constexpr int TOTC = OS + 1 + 96;
    constexpr int PSTR = 96*8 + 8;
    __shared__ __align__(16) float s_a[4*PSTR];
    __shared__ float s_pre[8][TOTC];

    const int t = threadIdx.x;
    const int n0 = blockIdx.x*8;
    const int nmax = min(8, N - n0);
    const size_t N96 = (size_t)N*96;

    for (int idx = t; idx < 8*96; idx += 256){
        int n = idx/96, k = idx - n*96;
        if (n < nmax) s_a[k*8 + n] = aggs[(size_t)(n0+n)*96 + k];
    }
    for (int idx = t; idx < 3*8*96; idx += 256){
        int p = idx/768, rem = idx - p*768;
        int n = rem/96, k = rem - n*96;
        if (n < nmax) s_a[(1+p)*PSTR + k*8 + n] = aggv[(size_t)p*N96 + (size_t)(n0+n)*96 + k];
    }
    __syncthreads();

    if (t < TOTC){
        const float* bp; int bstr; int plane;
        if (t < OS){ bp = W2s + t; bstr = OS; plane = 0; }
        else if (t == OS){ bp = W3; bstr = 1; plane = 0; }
        else { int q = t - OS - 1; int cv = q>>5, ww = q&31; bp = W2v + ww; bstr = 32; plane = 1+cv; }
        const float* ap = &s_a[plane*PSTR];

        float acc0=0,acc1=0,acc2=0,acc3=0,acc4=0,acc5=0,acc6=0,acc7=0;
        #pragma unroll 4
        for (int k = 0; k < 96; ++k){
            float b = bp[(size_t)k*bstr];
            float4 q0 = *reinterpret_cast<const float4*>(ap + k*8);
            float4 q1 = *reinterpret_cast<const float4*>(ap + k*8 + 4);
            acc0 += q0.x*b; acc1 += q0.y*b; acc2 += q0.z*b; acc3 += q0.w*b;
            acc4 += q1.x*b; acc5 += q1.y*b; acc6 += q1.z*b; acc7 += q1.w*b;
        }
        s_pre[0][t]=acc0; s_pre[1][t]=acc1; s_pre[2][t]=acc2; s_pre[3][t]=acc3;
        s_pre[4][t]=acc4; s_pre[5][t]=acc5; s_pre[6][t]=acc6; s_pre[7][t]=acc7;
    }
    __syncthreads();

    for (int idx = t; idx < nmax*192; idx += 256){
        int n = idx/192, r = idx - n*192;
        int gn = n0 + n;
        float sca = isd[gn]*attr[gn]*INV_SQRT96;
        float ang = 0.1f * s_pre[n][OS] * sca;
        float c_ = cosf(ang), s_ = sinf(ang);
        if (r < OS){
            float hs = c_*sc_s[(size_t)gn*OS + r] + s_*s_pre[n][r]*sca;
            if (FINAL) out_s[(size_t)gn*160 + r] = hs;
            else if (r < 64) out_s[(size_t)gn*64 + r] = siluf(hs);
        } else if (r >= 96){
            int q2 = r - 96;
            int ww = q2/3, c2 = q2 - 3*ww;
            float hv = c_*sc_v[(size_t)gn*96 + q2] + s_*s_pre[n][OS+1 + c2*32 + ww]*sca;
            if (FINAL){
                out_s[(size_t)gn*160 + 64 + q2] = hv;
            } else {
                float hs64 = c_*sc_s[(size_t)gn*OS + 64 + ww] + s_*s_pre[n][64 + ww]*sca;
                float sg = 1.f/(1.f + __expf(-hs64));
                out_v[(size_t)gn*96 + q2] = sg*hv;
            }
        }
    }
}

// ---------------- launch ----------------
extern "C" void kernel_launch(void* const* d_in, const int* in_sizes, int n_in,
                              void* d_out, int out_size, void* d_ws, size_t ws_size,
                              hipStream_t stream)
{
    const float* nf    = (const float*)d_in[0];
    const float* nattr = (const float*)d_in[1];
    const int*   esrc  = (const int*)  d_in[2];
    const int*   edst  = (const int*)  d_in[3];
    const float* eattr = (const float*)d_in[4];
    const float* escal = (const float*)d_in[5];
    const float* p1_sc_s = (const float*)d_in[6];
    const float* p1_sc_v = (const float*)d_in[7];
    const float* p1_l1_s = (const float*)d_in[8];
    const float* p1_l1_v = (const float*)d_in[9];
    const float* p1_fa   = (const float*)d_in[10];
    const float* p1_fb   = (const float*)d_in[11];
    const float* p1_l2_s = (const float*)d_in[12];
    const float* p1_l2_v = (const float*)d_in[13];
    const float* p1_l3   = (const float*)d_in[14];
    const float* p2_sc_s = (const float*)d_in[15];
    const float* p2_sc_v = (const float*)d_in[16];
    const float* p2_l1_s = (const float*)d_in[17];
    const float* p2_l1_v = (const float*)d_in[18];
    const float* p2_fa   = (const float*)d_in[19];
    const float* p2_fb   = (const float*)d_in[20];
    const float* p2_l2_s = (const float*)d_in[21];
    const float* p2_l2_v = (const float*)d_in[22];
    const float* p2_l3   = (const float*)d_in[23];

    const int N = in_sizes[1];
    const int E = in_sizes[2];

    // ---- workspace layout ----
    char* wsb = (char*)d_ws;
    __half* w_s     = (__half*)wsb;   wsb += (size_t)E*WN*2;   // slabs reuse low region
    float4* eattr_s = (float4*)wsb;   wsb += (size_t)E*16;
    __half* Wc1 = (__half*)wsb;       wsb += (size_t)(256*WPAD)*2;
    __half* Wc2 = (__half*)wsb;       wsb += (size_t)(256*WPAD)*2;
    __half* Bs1 = (__half*)wsb;       wsb += (size_t)(160*72)*2;
    __half* Bs2 = (__half*)wsb;       wsb += (size_t)(128*72)*2;
    __half* Bv1 = (__half*)wsb;       wsb += (size_t)(64*40)*2;
    __half* Bv2 = (__half*)wsb;       wsb += (size_t)(64*40)*2;
    __half* fs  = (__half*)wsb;       wsb += (size_t)N*64*2;
    __half* fv  = (__half*)wsb;       wsb += (size_t)N*96*2;
    float* scs  = (float*)wsb;        wsb += (size_t)N*96*4;
    float* scv  = (float*)wsb;        wsb += (size_t)N*96*4;
    float* gs   = (float*)wsb;        wsb += (size_t)N*64*4;
    float* gv   = (float*)wsb;        wsb += (size_t)N*96*4;
    float* aggs = (float*)wsb;        wsb += (size_t)N*96*4;
    float* aggv = (float*)wsb;        wsb += (size_t)N*96*3*4;
    float* isd  = (float*)wsb;        wsb += (size_t)N*4;
    int* cnt       = (int*)wsb;       wsb += (size_t)N*4;
    int* row_start = (int*)wsb;       wsb += (size_t)(N+1)*4;
    int* cursor    = (int*)wsb;       wsb += (size_t)N*4;
    int* perm      = (int*)wsb;       wsb += (size_t)E*4;
    int* esrc_s    = (int*)wsb;       wsb += (size_t)E*4;

    // ---- sort edges by dst + weight prep ----
    hipMemsetAsync(cnt, 0, (size_t)N*4, stream);
    hist_kernel<<<(E+255)/256, 256, 0, stream>>>(edst, cnt, E);
    scan_kernel<<<1, 1024, 0, stream>>>(cnt, row_start, cursor, N, E);
    scatter_kernel<<<(E+255)/256, 256, 0, stream>>>(edst, esrc, (const float4*)eattr,
                                                    cursor, perm, eattr_s, esrc_s, E);
    isd_kernel<<<(N+255)/256, 256, 0, stream>>>(cnt, isd, N);
    wprep<<<(256*WPAD+255)/256, 256, 0, stream>>>(p1_fa, p1_fb, p2_fa, p2_fb, Wc1, Wc2);
    wprep_pre<<<(160*72+128*72+2*64*40+255)/256, 256, 0, stream>>>(
        p1_l1_s, p1_sc_s, p1_l1_v, p1_sc_v,
        p2_l1_s, p2_sc_s, p2_l1_v, p2_sc_v, Bs1, Bs2, Bv1, Bv2);

    const int pre_grid  = (N + 63)/64;
    const int post_grid = (N + 7)/8;
    const int slabN = (N + NSLABS - 1)/NSLABS;
    const int mlp_grid = 768;   // grid-stride: ~3-4 tiles/block, amortizes weight staging

    // ---- conv1 ----
    node_pre_mfma<96><<<pre_grid, 256, 0, stream>>>(nf, 160, nf+64, 160, nattr,
        Bs1, Bv1, fs, scs, fv, scv, N);
    for (int s = 0; s < NSLABS; ++s){
        int n0 = s*slabN; if (n0 >= N) break;
        int n1 = (n0 + slabN < N) ? n0 + slabN : N;
        mlp_gemm_slab<<<mlp_grid, 256, 0, stream>>>(row_start, n0, n1, perm, escal,
                                                    Wc1, w_s, E);
        agg_slab<<<n1 - n0, 128, 0, stream>>>(row_start, n0, w_s,
                                              esrc_s, eattr_s, fs, fv, aggs, aggv, N);
    }
    post_fused<96, false><<<post_grid, 256, 0, stream>>>(aggs, aggv,
        p1_l2_s, p1_l2_v, p1_l3, isd, nattr, scs, scv, gs, gv, N);

    // ---- conv2 ----
    node_pre_mfma<64><<<pre_grid, 256, 0, stream>>>(gs, 64, gv, 96, nattr,
        Bs2, Bv2, fs, scs, fv, scv, N);
    for (int s = 0; s < NSLABS; ++s){
        int n0 = s*slabN; if (n0 >= N) break;
        int n1 = (n0 + slabN < N) ? n0 + slabN : N;
        mlp_gemm_slab<<<mlp_grid, 256, 0, stream>>>(row_start, n0, n1, perm, escal,
                                                    Wc2, w_s, E);
        agg_slab<<<n1 - n0, 128, 0, stream>>>(row_start, n0, w_s,
                                              esrc_s, eattr_s, fs, fv, aggs, aggv, N);
    }
    post_fused<64, true><<<post_grid, 256, 0, stream>>>(aggs, aggv,
        p2_l2_s, p2_l2_v, p2_l3, isd, nattr, scs, scv, (float*)d_out, nullptr, N);
}